// Round 1
// baseline (4804.362 us; speedup 1.0000x reference)
//
#include <hip/hip_runtime.h>
#include <math.h>

#define TT 2080
#define DM 512
#define DI 2048
#define NH 8
#define DH 64
#define NMTOK 16
#define NLAYER 4
#define QKV_N 1536
#define ATT_SCALE 0.125f

// ---------------- build w (concat mem|emb|mem) and pos_emb ----------------
__global__ __launch_bounds__(256) void k_build(const float* __restrict__ we,
                                               const float* __restrict__ mem,
                                               float* __restrict__ w,
                                               float* __restrict__ pos) {
  int idx = blockIdx.x * 256 + threadIdx.x;
  if (idx >= TT * DM) return;
  int t = idx >> 9, d = idx & 511;
  float v;
  if (t < NMTOK) v = mem[t * DM + d];
  else if (t < NMTOK + 2048) v = we[(t - NMTOK) * DM + d];
  else v = mem[(t - (NMTOK + 2048)) * DM + d];
  w[idx] = v;
  float p = (float)(TT - 1 - t);
  int i2 = d & 255;
  float freq = 1.0f / powf(10000.f, ((float)(2 * i2)) / 512.f);
  float ang = p * freq;
  pos[idx] = (d < 256) ? sinf(ang) : cosf(ang);
}

// ---------------- fp32 tiled GEMM: C[M,N] = A[M,K] @ B[K,N] (+bias)(+relu) --
// fuse: 0 = none, 1 = +bias, 2 = +bias then relu
__global__ __launch_bounds__(256) void k_gemm(const float* __restrict__ A,
                                              const float* __restrict__ B,
                                              const float* __restrict__ bias,
                                              float* __restrict__ C,
                                              int M, int N, int K, int fuse) {
  __shared__ float As[16][68];  // As[k][m]
  __shared__ float Bs[16][68];  // Bs[k][n]
  const int tid = threadIdx.x;
  const int m0 = blockIdx.y * 64, n0 = blockIdx.x * 64;
  const int tx = tid & 15, ty = tid >> 4;
  float acc[4][4];
#pragma unroll
  for (int a = 0; a < 4; ++a)
#pragma unroll
    for (int b = 0; b < 4; ++b) acc[a][b] = 0.f;

  for (int k0 = 0; k0 < K; k0 += 16) {
    __syncthreads();
#pragma unroll
    for (int i = 0; i < 4; ++i) {
      int e = tid + 256 * i;
      int rA = e >> 4, cA = e & 15;
      As[cA][rA] = (m0 + rA < M) ? A[(size_t)(m0 + rA) * K + k0 + cA] : 0.f;
      int rB = e >> 6, cB = e & 63;
      Bs[rB][cB] = B[(size_t)(k0 + rB) * N + n0 + cB];
    }
    __syncthreads();
#pragma unroll
    for (int kk = 0; kk < 16; ++kk) {
      float4 a4 = *(const float4*)&As[kk][ty * 4];
      float4 b4 = *(const float4*)&Bs[kk][tx * 4];
      float ar[4] = {a4.x, a4.y, a4.z, a4.w};
      float br[4] = {b4.x, b4.y, b4.z, b4.w};
#pragma unroll
      for (int a = 0; a < 4; ++a)
#pragma unroll
        for (int b = 0; b < 4; ++b) acc[a][b] += ar[a] * br[b];
    }
  }
#pragma unroll
  for (int a = 0; a < 4; ++a) {
    int m = m0 + ty * 4 + a;
    if (m < M) {
      float vv[4];
#pragma unroll
      for (int b = 0; b < 4; ++b) {
        int n = n0 + tx * 4 + b;
        float v = acc[a][b];
        if (fuse >= 1) v += bias[n];
        if (fuse == 2) v = fmaxf(v, 0.f);
        vv[b] = v;
      }
      float4 o = make_float4(vv[0], vv[1], vv[2], vv[3]);
      *(float4*)&C[(size_t)m * N + n0 + tx * 4] = o;
    }
  }
}

// ---------------- flash attention with XL relative shift + mem blocks ------
// qkv: [T][1536] (q|k|v), r: [T][512], attn out: [T][512]
__global__ __launch_bounds__(256) void k_attn(const float* __restrict__ qkv,
                                              const float* __restrict__ r,
                                              const float* __restrict__ rwb,
                                              const float* __restrict__ rrb,
                                              float* __restrict__ attn) {
  const int h = blockIdx.y;
  const int qt = 64 - blockIdx.x;  // heavy q-tiles dispatch first
  const int i0 = qt * 32;
  const int tid = threadIdx.x;

  __shared__ float qw[32][68], qr[32][68], ks[32][68], vs[32][68];
  __shared__ float rb[64][68];   // r band for BD (j<=i)
  __shared__ float rm[14][68];   // r rows 0..13 for mem-block BD (j>i+1)
  __shared__ float st[32][33];   // score/prob tile
  __shared__ float m_s[32], l_s[32];

  for (int e = tid; e < 32 * 64; e += 256) {
    int rr = e >> 6, c = e & 63;
    float qv = qkv[(size_t)(i0 + rr) * QKV_N + h * DH + c];
    qw[rr][c] = qv + rwb[h * DH + c];
    qr[rr][c] = qv + rrb[h * DH + c];
  }
  for (int e = tid; e < 14 * 64; e += 256) {
    int rr = e >> 6, c = e & 63;
    rm[rr][c] = r[(size_t)rr * DM + h * DH + c];
  }
  if (tid < 32) { m_s[tid] = -INFINITY; l_s[tid] = 0.f; }

  float o[8];
#pragma unroll
  for (int u = 0; u < 8; ++u) o[u] = 0.f;

  const int ii = tid >> 3;   // q row in tile
  const int g = tid & 7;     // sub-group lane
  const int jjb = g * 4;     // 4 score cols in phase A
  const int db = g * 8;      // 8 output dims in phase B
  const int i = i0 + ii;

  for (int jt = 0; jt <= qt; ++jt) {
    const int j0 = jt * 32;
    __syncthreads();  // previous iteration done with LDS tiles
    for (int e = tid; e < 32 * 64; e += 256) {
      int rr = e >> 6, c = e & 63;
      ks[rr][c] = qkv[(size_t)(j0 + rr) * QKV_N + DM + h * DH + c];
      vs[rr][c] = qkv[(size_t)(j0 + rr) * QKV_N + 2 * DM + h * DH + c];
    }
    const int kb = TT - 1 + j0 - i0 - 31;  // band base: kidx = kb + (jj + 31 - ii)
    for (int e = tid; e < 64 * 64; e += 256) {
      int rr = e >> 6, c = e & 63;
      int kidx = kb + rr;
      rb[rr][c] = (kidx < TT) ? r[(size_t)kidx * DM + h * DH + c] : 0.f;
    }
    __syncthreads();

    // ---- scores: AC + banded BD ----
    float ac[4] = {0, 0, 0, 0}, bd[4] = {0, 0, 0, 0};
#pragma unroll 4
    for (int d4 = 0; d4 < 16; ++d4) {
      float4 qw4 = *(const float4*)&qw[ii][d4 * 4];
      float4 qr4 = *(const float4*)&qr[ii][d4 * 4];
#pragma unroll
      for (int u = 0; u < 4; ++u) {
        float4 k4 = *(const float4*)&ks[jjb + u][d4 * 4];
        ac[u] += qw4.x * k4.x + qw4.y * k4.y + qw4.z * k4.z + qw4.w * k4.w;
        float4 r4 = *(const float4*)&rb[jjb + u + 31 - ii][d4 * 4];
        bd[u] += qr4.x * r4.x + qr4.y * r4.y + qr4.z * r4.z + qr4.w * r4.w;
      }
    }
    float sreg[4];
#pragma unroll
    for (int u = 0; u < 4; ++u) {
      int j = j0 + jjb + u;
      float s;
      if (j <= i) {
        s = (ac[u] + bd[u]) * ATT_SCALE;
      } else {
        bool inmem = (i < NMTOK && j < NMTOK) ||
                     (i >= TT - NMTOK && j >= TT - NMTOK);
        if (!inmem) s = -1e30f;
        else if (j == i + 1) s = ac[u] * ATT_SCALE;  // rel_shift zero-pad entry
        else {
          // rel_shift wraps: BD = (q[i+1]+rrb) . r[j-i-2]
          float b2 = 0.f;
          const int rrow = j - i - 2;
          for (int d = 0; d < 64; ++d) b2 += qr[ii + 1][d] * rm[rrow][d];
          s = (ac[u] + b2) * ATT_SCALE;
        }
      }
      sreg[u] = s;
    }
    // ---- online softmax (8 threads per row) ----
    float tmax = fmaxf(fmaxf(sreg[0], sreg[1]), fmaxf(sreg[2], sreg[3]));
#pragma unroll
    for (int off = 1; off < 8; off <<= 1) tmax = fmaxf(tmax, __shfl_xor(tmax, off));
    const float mold = m_s[ii];
    const float mnew = fmaxf(mold, tmax);
    const float alpha = expf(mold - mnew);
    float psum = 0.f;
#pragma unroll
    for (int u = 0; u < 4; ++u) {
      float p = expf(sreg[u] - mnew);
      st[ii][jjb + u] = p;
      psum += p;
    }
#pragma unroll
    for (int off = 1; off < 8; off <<= 1) psum += __shfl_xor(psum, off);
    if (g == 0) { m_s[ii] = mnew; l_s[ii] = l_s[ii] * alpha + psum; }
    __syncthreads();

    // ---- O = O*alpha + P @ V ----
#pragma unroll
    for (int u = 0; u < 8; ++u) o[u] *= alpha;
    for (int jj = 0; jj < 32; ++jj) {
      float p = st[ii][jj];
      float4 v0 = *(const float4*)&vs[jj][db];
      float4 v1 = *(const float4*)&vs[jj][db + 4];
      o[0] += p * v0.x; o[1] += p * v0.y; o[2] += p * v0.z; o[3] += p * v0.w;
      o[4] += p * v1.x; o[5] += p * v1.y; o[6] += p * v1.z; o[7] += p * v1.w;
    }
  }
  __syncthreads();
  const float linv = 1.f / l_s[ii];
#pragma unroll
  for (int u = 0; u < 8; ++u) o[u] *= linv;
  float4 o0 = make_float4(o[0], o[1], o[2], o[3]);
  float4 o1 = make_float4(o[4], o[5], o[6], o[7]);
  *(float4*)&attn[(size_t)i * DM + h * DH + db] = o0;
  *(float4*)&attn[(size_t)i * DM + h * DH + db + 4] = o1;
}

// ---------------- w = LayerNorm(w + delta) * g + b (in place) -------------
__global__ __launch_bounds__(256) void k_addln(float* __restrict__ w,
                                               const float* __restrict__ delta,
                                               const float* __restrict__ gamma,
                                               const float* __restrict__ beta) {
  const int row = blockIdx.x;
  const int tid = threadIdx.x;
  __shared__ float red[4], red2[4];
  size_t base = (size_t)row * DM;
  float x0 = w[base + tid] + delta[base + tid];
  float x1 = w[base + tid + 256] + delta[base + tid + 256];
  float s = x0 + x1;
#pragma unroll
  for (int off = 1; off < 64; off <<= 1) s += __shfl_xor(s, off);
  if ((tid & 63) == 0) red[tid >> 6] = s;
  __syncthreads();
  float mu = (red[0] + red[1] + red[2] + red[3]) * (1.f / 512.f);
  float d0 = x0 - mu, d1 = x1 - mu;
  float v = d0 * d0 + d1 * d1;
#pragma unroll
  for (int off = 1; off < 64; off <<= 1) v += __shfl_xor(v, off);
  if ((tid & 63) == 0) red2[tid >> 6] = v;
  __syncthreads();
  float var = (red2[0] + red2[1] + red2[2] + red2[3]) * (1.f / 512.f);
  float rstd = rsqrtf(var + 1e-5f);
  w[base + tid] = d0 * rstd * gamma[tid] + beta[tid];
  w[base + tid + 256] = d1 * rstd * gamma[tid + 256] + beta[tid + 256];
}

__global__ __launch_bounds__(256) void k_copy(const float* __restrict__ src,
                                              float* __restrict__ dst) {
  int idx = blockIdx.x * 256 + threadIdx.x;
  if (idx < TT * DM) dst[idx] = src[idx];
}

extern "C" void kernel_launch(void* const* d_in, const int* in_sizes, int n_in,
                              void* d_out, int out_size, void* d_ws, size_t ws_size,
                              hipStream_t stream) {
  const float* we   = (const float*)d_in[0];
  const float* mem  = (const float*)d_in[1];
  const float* Wqkv = (const float*)d_in[2];
  const float* Wr   = (const float*)d_in[3];
  const float* Wo   = (const float*)d_in[4];
  const float* ln1s = (const float*)d_in[5];
  const float* ln1b = (const float*)d_in[6];
  const float* W1   = (const float*)d_in[7];
  const float* b1   = (const float*)d_in[8];
  const float* W2   = (const float*)d_in[9];
  const float* b2   = (const float*)d_in[10];
  const float* ln2s = (const float*)d_in[11];
  const float* ln2b = (const float*)d_in[12];
  const float* rwb  = (const float*)d_in[13];
  const float* rrb  = (const float*)d_in[14];

  // workspace layout (fp32), overlaid: 8,519,680 floats = 34.1 MB
  float* ws   = (float*)d_ws;
  float* w    = ws;                               // TT*DM
  float* pos  = w + (size_t)TT * DM;              // TT*DM
  float* qkv  = pos + (size_t)TT * DM;            // TT*1536  (ff1 overlays qkv+r)
  float* r    = qkv + (size_t)TT * QKV_N;         // TT*DM
  float* attn = r + (size_t)TT * DM;              // TT*DM    (ff2 overlays attn)
  float* proj = attn + (size_t)TT * DM;           // TT*DM
  float* ff1  = qkv;                              // TT*DI == TT*(1536+512)
  float* ff2  = attn;                             // TT*DM

  k_build<<<(TT * DM + 255) / 256, 256, 0, stream>>>(we, mem, w, pos);

  dim3 gQKV(QKV_N / 64, (TT + 63) / 64);
  dim3 gDM(DM / 64, (TT + 63) / 64);
  dim3 gDI(DI / 64, (TT + 63) / 64);
  dim3 gA(65, NH);

  for (int l = 0; l < NLAYER; ++l) {
    k_gemm<<<gQKV, 256, 0, stream>>>(w, Wqkv + (size_t)l * DM * QKV_N, nullptr,
                                     qkv, TT, QKV_N, DM, 0);
    k_gemm<<<gDM, 256, 0, stream>>>(pos, Wr + (size_t)l * DM * DM, nullptr,
                                    r, TT, DM, DM, 0);
    k_attn<<<gA, 256, 0, stream>>>(qkv, r, rwb, rrb, attn);
    k_gemm<<<gDM, 256, 0, stream>>>(attn, Wo + (size_t)l * DM * DM, nullptr,
                                    proj, TT, DM, DM, 0);
    k_addln<<<TT, 256, 0, stream>>>(w, proj, ln1s + (size_t)l * DM, ln1b + (size_t)l * DM);
    k_gemm<<<gDI, 256, 0, stream>>>(w, W1 + (size_t)l * DM * DI, b1 + (size_t)l * DI,
                                    ff1, TT, DI, DM, 2);
    k_gemm<<<gDM, 256, 0, stream>>>(ff1, W2 + (size_t)l * DI * DM, b2 + (size_t)l * DM,
                                    ff2, TT, DM, DI, 1);
    k_addln<<<TT, 256, 0, stream>>>(w, ff2, ln2s + (size_t)l * DM, ln2b + (size_t)l * DM);
  }
  k_copy<<<(TT * DM + 255) / 256, 256, 0, stream>>>(w, (float*)d_out);
}

// Round 2
// 2519.230 us; speedup vs baseline: 1.9071x; 1.9071x over previous
//
#include <hip/hip_runtime.h>
#include <hip/hip_bf16.h>
#include <math.h>

#define TT 2080
#define DM 512
#define DI 2048
#define NH 8
#define DH 64
#define NMTOK 16
#define NLAYER 4
#define QKV_N 1536
#define ATT_SCALE 0.125f

typedef short bf16x8 __attribute__((ext_vector_type(8)));
typedef float f32x4 __attribute__((ext_vector_type(4)));
typedef unsigned short ushort_t;

__device__ __forceinline__ ushort_t f2bf(float f) {
  __hip_bfloat16 h = __float2bfloat16(f);
  return *reinterpret_cast<ushort_t*>(&h);
}
__device__ __forceinline__ float bfbits2f(unsigned int hi_bits) {
  return __uint_as_float(hi_bits);
}
__device__ __forceinline__ void unpack8(uint4 v, float* f) {
  f[0] = bfbits2f(v.x << 16); f[1] = bfbits2f(v.x & 0xffff0000u);
  f[2] = bfbits2f(v.y << 16); f[3] = bfbits2f(v.y & 0xffff0000u);
  f[4] = bfbits2f(v.z << 16); f[5] = bfbits2f(v.z & 0xffff0000u);
  f[6] = bfbits2f(v.w << 16); f[7] = bfbits2f(v.w & 0xffff0000u);
}

// ---------------- build w (fp32+bf16) and pos_emb (bf16) ------------------
__global__ __launch_bounds__(256) void k_build(const float* __restrict__ we,
                                               const float* __restrict__ mem,
                                               float* __restrict__ w,
                                               ushort_t* __restrict__ wb,
                                               ushort_t* __restrict__ posb) {
  int idx = blockIdx.x * 256 + threadIdx.x;
  if (idx >= TT * DM) return;
  int t = idx >> 9, d = idx & 511;
  float v;
  if (t < NMTOK) v = mem[t * DM + d];
  else if (t < NMTOK + 2048) v = we[(t - NMTOK) * DM + d];
  else v = mem[(t - (NMTOK + 2048)) * DM + d];
  w[idx] = v;
  wb[idx] = f2bf(v);
  float p = (float)(TT - 1 - t);
  int i2 = d & 255;
  float freq = 1.0f / powf(10000.f, ((float)(2 * i2)) / 512.f);
  float ang = p * freq;
  posb[idx] = f2bf((d < 256) ? sinf(ang) : cosf(ang));
}

// ---------------- weight transpose + cast: src fp32 [K][N] -> dst bf16 [N][K]
__global__ __launch_bounds__(256) void k_transpose(const float* __restrict__ src,
                                                   ushort_t* __restrict__ dst,
                                                   int K, int N) {
  __shared__ float t[32][33];
  const int tid = threadIdx.x;
  const int n0 = blockIdx.x * 32, k0 = blockIdx.y * 32;
#pragma unroll
  for (int p = 0; p < 4; ++p) {
    int row = (tid >> 5) + 8 * p, col = tid & 31;
    t[row][col] = src[(size_t)(k0 + row) * N + n0 + col];
  }
  __syncthreads();
#pragma unroll
  for (int p = 0; p < 4; ++p) {
    int n = (tid >> 5) + 8 * p, k = tid & 31;
    dst[(size_t)(n0 + n) * K + k0 + k] = f2bf(t[k][n]);
  }
}

// ---------------- bf16 MFMA GEMM: C[M,N] = A[M,K] @ Bt[N,K]^T --------------
// flags: 1=+bias, 2=relu, 4=bf16 output (else fp32)
__global__ __launch_bounds__(256) void k_gemm_mfma(const ushort_t* __restrict__ A,
                                                   const ushort_t* __restrict__ Bt,
                                                   const float* __restrict__ bias,
                                                   float* __restrict__ C,
                                                   ushort_t* __restrict__ Cb,
                                                   int M, int N, int K, int flags) {
  __shared__ short As[64][72];
  __shared__ short Bs[64][72];
  const int tid = threadIdx.x;
  const int m0 = blockIdx.y * 64, n0 = blockIdx.x * 64;
  const int lane = tid & 63, wv = tid >> 6;
  const int wm = (wv >> 1) * 32, wn = (wv & 1) * 32;
  const int lm = lane & 15, quad = lane >> 4;

  f32x4 acc[2][2];
#pragma unroll
  for (int a = 0; a < 2; ++a)
#pragma unroll
    for (int b = 0; b < 2; ++b) acc[a][b] = (f32x4)(0.f);

  const uint4 zero4 = make_uint4(0, 0, 0, 0);
  for (int k0 = 0; k0 < K; k0 += 64) {
    __syncthreads();
#pragma unroll
    for (int p = 0; p < 2; ++p) {
      int e = tid + 256 * p;
      int row = e >> 3, c8 = (e & 7) * 8;
      uint4 av = (m0 + row < M)
                     ? *(const uint4*)&A[(size_t)(m0 + row) * K + k0 + c8]
                     : zero4;
      *(uint4*)&As[row][c8] = av;
      uint4 bv = *(const uint4*)&Bt[(size_t)(n0 + row) * K + k0 + c8];
      *(uint4*)&Bs[row][c8] = bv;
    }
    __syncthreads();
#pragma unroll
    for (int kk = 0; kk < 64; kk += 32) {
      bf16x8 a0 = *(const bf16x8*)&As[wm + lm][kk + quad * 8];
      bf16x8 a1 = *(const bf16x8*)&As[wm + 16 + lm][kk + quad * 8];
      bf16x8 b0 = *(const bf16x8*)&Bs[wn + lm][kk + quad * 8];
      bf16x8 b1 = *(const bf16x8*)&Bs[wn + 16 + lm][kk + quad * 8];
      acc[0][0] = __builtin_amdgcn_mfma_f32_16x16x32_bf16(a0, b0, acc[0][0], 0, 0, 0);
      acc[0][1] = __builtin_amdgcn_mfma_f32_16x16x32_bf16(a0, b1, acc[0][1], 0, 0, 0);
      acc[1][0] = __builtin_amdgcn_mfma_f32_16x16x32_bf16(a1, b0, acc[1][0], 0, 0, 0);
      acc[1][1] = __builtin_amdgcn_mfma_f32_16x16x32_bf16(a1, b1, acc[1][1], 0, 0, 0);
    }
  }
#pragma unroll
  for (int mt = 0; mt < 2; ++mt)
#pragma unroll
    for (int nt = 0; nt < 2; ++nt) {
      int col = n0 + wn + nt * 16 + lm;
      float bv = (flags & 1) ? bias[col] : 0.f;
#pragma unroll
      for (int t = 0; t < 4; ++t) {
        int row = m0 + wm + mt * 16 + quad * 4 + t;
        if (row < M) {
          float v = acc[mt][nt][t] + bv;
          if (flags & 2) v = fmaxf(v, 0.f);
          if (flags & 4) Cb[(size_t)row * N + col] = f2bf(v);
          else C[(size_t)row * N + col] = v;
        }
      }
    }
}

// ---------------- flash attention (bf16 inputs) with XL rel-shift ----------
__global__ __launch_bounds__(256) void k_attn(const ushort_t* __restrict__ qkv,
                                              const ushort_t* __restrict__ r,
                                              const float* __restrict__ rwb,
                                              const float* __restrict__ rrb,
                                              ushort_t* __restrict__ attn) {
  const int h = blockIdx.y;
  const int qt = 64 - blockIdx.x;  // heavy q-tiles dispatch first
  const int i0 = qt * 32;
  const int tid = threadIdx.x;

  __shared__ float qw[32][68], qr[32][68], ks[32][68], vs[32][68];
  __shared__ float rb[64][68];   // r band for BD (j<=i)
  __shared__ float rm[14][68];   // r rows 0..13 for mem-block BD (j>i+1)
  __shared__ float st[32][33];   // prob tile
  __shared__ float m_s[32], l_s[32];
  __shared__ float swb[64], srb[64];

  if (tid < 64) { swb[tid] = rwb[h * DH + tid]; srb[tid] = rrb[h * DH + tid]; }
  __syncthreads();

  {  // q staging: 32 rows x 8 chunks = 256
    int rr = tid >> 3, c8 = (tid & 7) * 8;
    uint4 qv = *(const uint4*)&qkv[(size_t)(i0 + rr) * QKV_N + h * DH + c8];
    float f[8]; unpack8(qv, f);
#pragma unroll
    for (int j = 0; j < 8; ++j) {
      qw[rr][c8 + j] = f[j] + swb[c8 + j];
      qr[rr][c8 + j] = f[j] + srb[c8 + j];
    }
  }
  if (tid < 14 * 8) {  // rm staging
    int rr = tid >> 3, c8 = (tid & 7) * 8;
    uint4 v = *(const uint4*)&r[(size_t)rr * DM + h * DH + c8];
    float f[8]; unpack8(v, f);
#pragma unroll
    for (int j = 0; j < 8; ++j) rm[rr][c8 + j] = f[j];
  }
  if (tid < 32) { m_s[tid] = -INFINITY; l_s[tid] = 0.f; }

  float o[8];
#pragma unroll
  for (int u = 0; u < 8; ++u) o[u] = 0.f;

  const int ii = tid >> 3;
  const int g = tid & 7;
  const int jjb = g * 4;
  const int db = g * 8;
  const int i = i0 + ii;

  for (int jt = 0; jt <= qt; ++jt) {
    const int j0 = jt * 32;
    __syncthreads();
    {  // k/v staging
      int rr = tid >> 3, c8 = (tid & 7) * 8;
      uint4 kv = *(const uint4*)&qkv[(size_t)(j0 + rr) * QKV_N + DM + h * DH + c8];
      uint4 vv = *(const uint4*)&qkv[(size_t)(j0 + rr) * QKV_N + 2 * DM + h * DH + c8];
      float fk[8], fv[8]; unpack8(kv, fk); unpack8(vv, fv);
#pragma unroll
      for (int j = 0; j < 8; ++j) { ks[rr][c8 + j] = fk[j]; vs[rr][c8 + j] = fv[j]; }
    }
    const int kb = TT - 1 + j0 - i0 - 31;  // kidx = kb + (jj + 31 - ii)
#pragma unroll
    for (int p = 0; p < 2; ++p) {  // r-band staging: 64 rows
      int e = tid + 256 * p;
      int rr = e >> 3, c8 = (e & 7) * 8;
      int kidx = kb + rr;
      float f[8];
      if (kidx < TT) {
        uint4 v = *(const uint4*)&r[(size_t)kidx * DM + h * DH + c8];
        unpack8(v, f);
      } else {
#pragma unroll
        for (int j = 0; j < 8; ++j) f[j] = 0.f;
      }
#pragma unroll
      for (int j = 0; j < 8; ++j) rb[rr][c8 + j] = f[j];
    }
    __syncthreads();

    // ---- scores: AC + banded BD ----
    float ac[4] = {0, 0, 0, 0}, bd[4] = {0, 0, 0, 0};
#pragma unroll 4
    for (int d4 = 0; d4 < 16; ++d4) {
      float4 qw4 = *(const float4*)&qw[ii][d4 * 4];
      float4 qr4 = *(const float4*)&qr[ii][d4 * 4];
#pragma unroll
      for (int u = 0; u < 4; ++u) {
        float4 k4 = *(const float4*)&ks[jjb + u][d4 * 4];
        ac[u] += qw4.x * k4.x + qw4.y * k4.y + qw4.z * k4.z + qw4.w * k4.w;
        float4 r4 = *(const float4*)&rb[jjb + u + 31 - ii][d4 * 4];
        bd[u] += qr4.x * r4.x + qr4.y * r4.y + qr4.z * r4.z + qr4.w * r4.w;
      }
    }
    float sreg[4];
#pragma unroll
    for (int u = 0; u < 4; ++u) {
      int j = j0 + jjb + u;
      float s;
      if (j <= i) {
        s = (ac[u] + bd[u]) * ATT_SCALE;
      } else {
        bool inmem = (i < NMTOK && j < NMTOK) ||
                     (i >= TT - NMTOK && j >= TT - NMTOK);
        if (!inmem) s = -1e30f;
        else if (j == i + 1) s = ac[u] * ATT_SCALE;  // rel_shift zero-pad entry
        else {
          float b2 = 0.f;
          const int rrow = j - i - 2;
          for (int d = 0; d < 64; ++d) b2 += qr[ii + 1][d] * rm[rrow][d];
          s = (ac[u] + b2) * ATT_SCALE;
        }
      }
      sreg[u] = s;
    }
    // ---- online softmax (8 threads per row) ----
    float tmax = fmaxf(fmaxf(sreg[0], sreg[1]), fmaxf(sreg[2], sreg[3]));
#pragma unroll
    for (int off = 1; off < 8; off <<= 1) tmax = fmaxf(tmax, __shfl_xor(tmax, off));
    const float mold = m_s[ii];
    const float mnew = fmaxf(mold, tmax);
    const float alpha = expf(mold - mnew);
    float psum = 0.f;
#pragma unroll
    for (int u = 0; u < 4; ++u) {
      float p = expf(sreg[u] - mnew);
      st[ii][jjb + u] = p;
      psum += p;
    }
#pragma unroll
    for (int off = 1; off < 8; off <<= 1) psum += __shfl_xor(psum, off);
    if (g == 0) { m_s[ii] = mnew; l_s[ii] = l_s[ii] * alpha + psum; }
    __syncthreads();

    // ---- O = O*alpha + P @ V ----
#pragma unroll
    for (int u = 0; u < 8; ++u) o[u] *= alpha;
    for (int jj = 0; jj < 32; ++jj) {
      float p = st[ii][jj];
      float4 v0 = *(const float4*)&vs[jj][db];
      float4 v1 = *(const float4*)&vs[jj][db + 4];
      o[0] += p * v0.x; o[1] += p * v0.y; o[2] += p * v0.z; o[3] += p * v0.w;
      o[4] += p * v1.x; o[5] += p * v1.y; o[6] += p * v1.z; o[7] += p * v1.w;
    }
  }
  __syncthreads();
  const float linv = 1.f / l_s[ii];
  ushort_t ob[8];
#pragma unroll
  for (int u = 0; u < 8; ++u) ob[u] = f2bf(o[u] * linv);
  *(uint4*)&attn[(size_t)i * DM + h * DH + db] = *(uint4*)ob;
}

// ---------------- w = LayerNorm(w + delta) * g + b; writes fp32 + bf16 ----
__global__ __launch_bounds__(256) void k_addln(float* __restrict__ w,
                                               ushort_t* __restrict__ wb,
                                               const float* __restrict__ delta,
                                               const float* __restrict__ gamma,
                                               const float* __restrict__ beta) {
  const int row = blockIdx.x;
  const int tid = threadIdx.x;
  __shared__ float red[4], red2[4];
  size_t base = (size_t)row * DM;
  float x0 = w[base + tid] + delta[base + tid];
  float x1 = w[base + tid + 256] + delta[base + tid + 256];
  float s = x0 + x1;
#pragma unroll
  for (int off = 1; off < 64; off <<= 1) s += __shfl_xor(s, off);
  if ((tid & 63) == 0) red[tid >> 6] = s;
  __syncthreads();
  float mu = (red[0] + red[1] + red[2] + red[3]) * (1.f / 512.f);
  float d0 = x0 - mu, d1 = x1 - mu;
  float v = d0 * d0 + d1 * d1;
#pragma unroll
  for (int off = 1; off < 64; off <<= 1) v += __shfl_xor(v, off);
  if ((tid & 63) == 0) red2[tid >> 6] = v;
  __syncthreads();
  float var = (red2[0] + red2[1] + red2[2] + red2[3]) * (1.f / 512.f);
  float rstd = rsqrtf(var + 1e-5f);
  float o0 = d0 * rstd * gamma[tid] + beta[tid];
  float o1 = d1 * rstd * gamma[tid + 256] + beta[tid + 256];
  w[base + tid] = o0;
  w[base + tid + 256] = o1;
  wb[base + tid] = f2bf(o0);
  wb[base + tid + 256] = f2bf(o1);
}

__global__ __launch_bounds__(256) void k_copy(const float* __restrict__ src,
                                              float* __restrict__ dst) {
  int idx = blockIdx.x * 256 + threadIdx.x;
  if (idx < TT * DM) dst[idx] = src[idx];
}

extern "C" void kernel_launch(void* const* d_in, const int* in_sizes, int n_in,
                              void* d_out, int out_size, void* d_ws, size_t ws_size,
                              hipStream_t stream) {
  const float* we   = (const float*)d_in[0];
  const float* mem  = (const float*)d_in[1];
  const float* Wqkv = (const float*)d_in[2];
  const float* Wr   = (const float*)d_in[3];
  const float* Wo   = (const float*)d_in[4];
  const float* ln1s = (const float*)d_in[5];
  const float* ln1b = (const float*)d_in[6];
  const float* W1   = (const float*)d_in[7];
  const float* b1   = (const float*)d_in[8];
  const float* W2   = (const float*)d_in[9];
  const float* b2   = (const float*)d_in[10];
  const float* ln2s = (const float*)d_in[11];
  const float* ln2b = (const float*)d_in[12];
  const float* rwb  = (const float*)d_in[13];
  const float* rrb  = (const float*)d_in[14];

  // ---- workspace layout (~25.5 MB) ----
  float* w     = (float*)d_ws;                        // TT*DM fp32
  float* proj  = w + (size_t)TT * DM;                 // TT*DM fp32 (ff2 overlays)
  ushort_t* wb    = (ushort_t*)(proj + (size_t)TT * DM);  // TT*DM bf16
  ushort_t* posb  = wb + (size_t)TT * DM;             // TT*DM bf16
  ushort_t* attnb = posb + (size_t)TT * DM;           // TT*DM bf16
  ushort_t* qkvb  = attnb + (size_t)TT * DM;          // TT*1536 bf16 (ff1b overlays qkvb+rbg)
  ushort_t* rbg   = qkvb + (size_t)TT * QKV_N;        // TT*DM bf16
  ushort_t* Wt    = rbg + (size_t)TT * DM;            // max 2048*512 bf16 (per-GEMM transposed weight)
  ushort_t* ff1b  = qkvb;                             // TT*DI bf16 == qkvb+rbg exactly
  float* ff2   = proj;

  k_build<<<(TT * DM + 255) / 256, 256, 0, stream>>>(we, mem, w, wb, posb);

  dim3 gQKV(QKV_N / 64, 33), gDMg(DM / 64, 33), gDIg(DI / 64, 33);
  dim3 gA(65, NH);
  dim3 tQKV(QKV_N / 32, DM / 32), tDM(DM / 32, DM / 32);
  dim3 tW1(DI / 32, DM / 32), tW2(DM / 32, DI / 32);

  for (int l = 0; l < NLAYER; ++l) {
    k_transpose<<<tQKV, 256, 0, stream>>>(Wqkv + (size_t)l * DM * QKV_N, Wt, DM, QKV_N);
    k_gemm_mfma<<<gQKV, 256, 0, stream>>>(wb, Wt, nullptr, nullptr, qkvb,
                                          TT, QKV_N, DM, 4);
    k_transpose<<<tDM, 256, 0, stream>>>(Wr + (size_t)l * DM * DM, Wt, DM, DM);
    k_gemm_mfma<<<gDMg, 256, 0, stream>>>(posb, Wt, nullptr, nullptr, rbg,
                                          TT, DM, DM, 4);
    k_attn<<<gA, 256, 0, stream>>>(qkvb, rbg, rwb, rrb, attnb);
    k_transpose<<<tDM, 256, 0, stream>>>(Wo + (size_t)l * DM * DM, Wt, DM, DM);
    k_gemm_mfma<<<gDMg, 256, 0, stream>>>(attnb, Wt, nullptr, proj, nullptr,
                                          TT, DM, DM, 0);
    k_addln<<<TT, 256, 0, stream>>>(w, wb, proj, ln1s + (size_t)l * DM, ln1b + (size_t)l * DM);
    k_transpose<<<tW1, 256, 0, stream>>>(W1 + (size_t)l * DM * DI, Wt, DM, DI);
    k_gemm_mfma<<<gDIg, 256, 0, stream>>>(wb, Wt, b1 + (size_t)l * DI, nullptr, ff1b,
                                          TT, DI, DM, 1 | 2 | 4);
    k_transpose<<<tW2, 256, 0, stream>>>(W2 + (size_t)l * DI * DM, Wt, DI, DM);
    k_gemm_mfma<<<gDMg, 256, 0, stream>>>(ff1b, Wt, b2 + (size_t)l * DM, ff2, nullptr,
                                          TT, DM, DI, 1);
    k_addln<<<TT, 256, 0, stream>>>(w, wb, ff2, ln2s + (size_t)l * DM, ln2b + (size_t)l * DM);
  }
  k_copy<<<(TT * DM + 255) / 256, 256, 0, stream>>>(w, (float*)d_out);
}

// Round 3
// 1222.517 us; speedup vs baseline: 3.9299x; 2.0607x over previous
//
#include <hip/hip_runtime.h>
#include <hip/hip_bf16.h>
#include <math.h>

#define TT 2080
#define DM 512
#define DI 2048
#define NH 8
#define DH 64
#define NMTOK 16
#define NLAYER 4
#define QKV_N 1536
#define ATT_SCALE 0.125f

typedef short bf16x8 __attribute__((ext_vector_type(8)));
typedef float f32x4 __attribute__((ext_vector_type(4)));
typedef unsigned short ushort_t;

__device__ __forceinline__ ushort_t f2bf(float f) {
  __hip_bfloat16 h = __float2bfloat16(f);
  return *reinterpret_cast<ushort_t*>(&h);
}
__device__ __forceinline__ float bfbits2f(unsigned int hi_bits) {
  return __uint_as_float(hi_bits);
}
__device__ __forceinline__ void unpack8(uint4 v, float* f) {
  f[0] = bfbits2f(v.x << 16); f[1] = bfbits2f(v.x & 0xffff0000u);
  f[2] = bfbits2f(v.y << 16); f[3] = bfbits2f(v.y & 0xffff0000u);
  f[4] = bfbits2f(v.z << 16); f[5] = bfbits2f(v.z & 0xffff0000u);
  f[6] = bfbits2f(v.w << 16); f[7] = bfbits2f(v.w & 0xffff0000u);
}
__device__ __forceinline__ unsigned int pack2(ushort_t lo, ushort_t hi) {
  return (unsigned int)lo | ((unsigned int)hi << 16);
}

// ---------------- build w (fp32+bf16) and pos_emb (bf16) ------------------
__global__ __launch_bounds__(256) void k_build(const float* __restrict__ we,
                                               const float* __restrict__ mem,
                                               float* __restrict__ w,
                                               ushort_t* __restrict__ wb,
                                               ushort_t* __restrict__ posb) {
  int idx = blockIdx.x * 256 + threadIdx.x;
  if (idx >= TT * DM) return;
  int t = idx >> 9, d = idx & 511;
  float v;
  if (t < NMTOK) v = mem[t * DM + d];
  else if (t < NMTOK + 2048) v = we[(t - NMTOK) * DM + d];
  else v = mem[(t - (NMTOK + 2048)) * DM + d];
  w[idx] = v;
  wb[idx] = f2bf(v);
  float p = (float)(TT - 1 - t);
  int i2 = d & 255;
  float freq = 1.0f / powf(10000.f, ((float)(2 * i2)) / 512.f);
  float ang = p * freq;
  posb[idx] = f2bf((d < 256) ? sinf(ang) : cosf(ang));
}

// ---------------- weight transpose + cast: src fp32 [K][N] -> dst bf16 [N][K]
__global__ __launch_bounds__(256) void k_transpose(const float* __restrict__ src,
                                                   ushort_t* __restrict__ dst,
                                                   int K, int N) {
  __shared__ float t[32][33];
  const int tid = threadIdx.x;
  const int n0 = blockIdx.x * 32, k0 = blockIdx.y * 32;
#pragma unroll
  for (int p = 0; p < 4; ++p) {
    int row = (tid >> 5) + 8 * p, col = tid & 31;
    t[row][col] = src[(size_t)(k0 + row) * N + n0 + col];
  }
  __syncthreads();
#pragma unroll
  for (int p = 0; p < 4; ++p) {
    int n = (tid >> 5) + 8 * p, k = tid & 31;
    dst[(size_t)(n0 + n) * K + k0 + k] = f2bf(t[k][n]);
  }
}

// ---------------- bf16 MFMA GEMM: C[M,N] = A[M,K] @ Bt[N,K]^T --------------
// flags: 1=+bias, 2=relu, 4=bf16 output (else fp32)
__global__ __launch_bounds__(256) void k_gemm_mfma(const ushort_t* __restrict__ A,
                                                   const ushort_t* __restrict__ Bt,
                                                   const float* __restrict__ bias,
                                                   float* __restrict__ C,
                                                   ushort_t* __restrict__ Cb,
                                                   int M, int N, int K, int flags) {
  __shared__ short As[64][72];
  __shared__ short Bs[64][72];
  const int tid = threadIdx.x;
  const int m0 = blockIdx.y * 64, n0 = blockIdx.x * 64;
  const int lane = tid & 63, wv = tid >> 6;
  const int wm = (wv >> 1) * 32, wn = (wv & 1) * 32;
  const int lm = lane & 15, quad = lane >> 4;

  f32x4 acc[2][2];
#pragma unroll
  for (int a = 0; a < 2; ++a)
#pragma unroll
    for (int b = 0; b < 2; ++b) acc[a][b] = (f32x4)(0.f);

  const uint4 zero4 = make_uint4(0, 0, 0, 0);
  for (int k0 = 0; k0 < K; k0 += 64) {
    __syncthreads();
#pragma unroll
    for (int p = 0; p < 2; ++p) {
      int e = tid + 256 * p;
      int row = e >> 3, c8 = (e & 7) * 8;
      uint4 av = (m0 + row < M)
                     ? *(const uint4*)&A[(size_t)(m0 + row) * K + k0 + c8]
                     : zero4;
      *(uint4*)&As[row][c8] = av;
      uint4 bv = *(const uint4*)&Bt[(size_t)(n0 + row) * K + k0 + c8];
      *(uint4*)&Bs[row][c8] = bv;
    }
    __syncthreads();
#pragma unroll
    for (int kk = 0; kk < 64; kk += 32) {
      bf16x8 a0 = *(const bf16x8*)&As[wm + lm][kk + quad * 8];
      bf16x8 a1 = *(const bf16x8*)&As[wm + 16 + lm][kk + quad * 8];
      bf16x8 b0 = *(const bf16x8*)&Bs[wn + lm][kk + quad * 8];
      bf16x8 b1 = *(const bf16x8*)&Bs[wn + 16 + lm][kk + quad * 8];
      acc[0][0] = __builtin_amdgcn_mfma_f32_16x16x32_bf16(a0, b0, acc[0][0], 0, 0, 0);
      acc[0][1] = __builtin_amdgcn_mfma_f32_16x16x32_bf16(a0, b1, acc[0][1], 0, 0, 0);
      acc[1][0] = __builtin_amdgcn_mfma_f32_16x16x32_bf16(a1, b0, acc[1][0], 0, 0, 0);
      acc[1][1] = __builtin_amdgcn_mfma_f32_16x16x32_bf16(a1, b1, acc[1][1], 0, 0, 0);
    }
  }
#pragma unroll
  for (int mt = 0; mt < 2; ++mt)
#pragma unroll
    for (int nt = 0; nt < 2; ++nt) {
      int col = n0 + wn + nt * 16 + lm;
      float bv = (flags & 1) ? bias[col] : 0.f;
#pragma unroll
      for (int t = 0; t < 4; ++t) {
        int row = m0 + wm + mt * 16 + quad * 4 + t;
        if (row < M) {
          float v = acc[mt][nt][t] + bv;
          if (flags & 2) v = fmaxf(v, 0.f);
          if (flags & 4) Cb[(size_t)row * N + col] = f2bf(v);
          else C[(size_t)row * N + col] = v;
        }
      }
    }
}

// ---------------- MFMA flash attention with XL rel-shift -------------------
// AC = (q+rwb)K^T via MFMA; BDfull = (q+rrb)Rband^T via MFMA, rel-shift as
// LDS diagonal gather; PV as O^T = V^T P^T via MFMA (V staged transposed,
// P round-tripped through LDS). Mem-block exceptions stay scalar (rare).
__global__ __launch_bounds__(256) void k_attn(const ushort_t* __restrict__ qkv,
                                              const ushort_t* __restrict__ r,
                                              const float* __restrict__ rwb,
                                              const float* __restrict__ rrb,
                                              ushort_t* __restrict__ attn) {
  const int h = blockIdx.y;
  const int qt = 64 - blockIdx.x;  // heavy q-tiles dispatch first
  const int i0 = qt * 32;
  const int tid = threadIdx.x;
  const int lane = tid & 63, wv = tid >> 6;
  const int lm = lane & 15, quad = lane >> 4;

  __shared__ short qw[32][72];     // (q+rwb) bf16, [i][d]
  __shared__ short qr[33][72];     // (q+rrb) bf16, [i][d] (+1 safety row)
  __shared__ short ks_[32][72];    // K tile [j][d]
  __shared__ short vsT[64][40];    // V^T tile [d][j]
  __shared__ short rband[64][72];  // r band [t][d], kidx = kb + t
  __shared__ short pb[32][40];     // P bf16 [i][j]
  __shared__ float rm[14][68];     // r rows 0..13 fp32 (mem-block wrap)
  __shared__ float st[32][33];     // AC fp32 [i][j]
  __shared__ float bdf[32][66];    // BDfull fp32 [i][t]
  __shared__ float m_s[32], l_s[32], alpha_s[32];

  {  // stage qw/qr with bias add
    int rr = tid >> 3, c8 = (tid & 7) * 8;
    uint4 qv = *(const uint4*)&qkv[(size_t)(i0 + rr) * QKV_N + h * DH + c8];
    float f[8]; unpack8(qv, f);
    float4 w0 = *(const float4*)&rwb[h * DH + c8];
    float4 w1 = *(const float4*)&rwb[h * DH + c8 + 4];
    float4 r0 = *(const float4*)&rrb[h * DH + c8];
    float4 r1 = *(const float4*)&rrb[h * DH + c8 + 4];
    uint4 ow, orr;
    ow.x = pack2(f2bf(f[0] + w0.x), f2bf(f[1] + w0.y));
    ow.y = pack2(f2bf(f[2] + w0.z), f2bf(f[3] + w0.w));
    ow.z = pack2(f2bf(f[4] + w1.x), f2bf(f[5] + w1.y));
    ow.w = pack2(f2bf(f[6] + w1.z), f2bf(f[7] + w1.w));
    orr.x = pack2(f2bf(f[0] + r0.x), f2bf(f[1] + r0.y));
    orr.y = pack2(f2bf(f[2] + r0.z), f2bf(f[3] + r0.w));
    orr.z = pack2(f2bf(f[4] + r1.x), f2bf(f[5] + r1.y));
    orr.w = pack2(f2bf(f[6] + r1.z), f2bf(f[7] + r1.w));
    *(uint4*)&qw[rr][c8] = ow;
    *(uint4*)&qr[rr][c8] = orr;
  }
  if (tid < 112) {  // rm staging (fp32)
    int rr = tid >> 3, c8 = (tid & 7) * 8;
    uint4 v = *(const uint4*)&r[(size_t)rr * DM + h * DH + c8];
    float f[8]; unpack8(v, f);
#pragma unroll
    for (int j = 0; j < 8; ++j) rm[rr][c8 + j] = f[j];
  }
  if (tid < 32) { m_s[tid] = -INFINITY; l_s[tid] = 0.f; }

  f32x4 oA = (f32x4)(0.f);  // O^T accum, dtile=wv, itile 0 (i = i0+lm)
  f32x4 oB = (f32x4)(0.f);  // itile 1 (i = i0+16+lm)

  const uint4 zero4 = make_uint4(0, 0, 0, 0);
  for (int jt = 0; jt <= qt; ++jt) {
    const int j0 = jt * 32;
    __syncthreads();  // prior PV done with vsT/pb; staging may overwrite
    {  // stage K tile + V^T tile
      int rr = tid >> 3, c8 = (tid & 7) * 8;
      uint4 kv = *(const uint4*)&qkv[(size_t)(j0 + rr) * QKV_N + DM + h * DH + c8];
      *(uint4*)&ks_[rr][c8] = kv;
      uint4 vv = *(const uint4*)&qkv[(size_t)(j0 + rr) * QKV_N + 2 * DM + h * DH + c8];
      ushort_t s[8];
      s[0] = (ushort_t)(vv.x & 0xffffu); s[1] = (ushort_t)(vv.x >> 16);
      s[2] = (ushort_t)(vv.y & 0xffffu); s[3] = (ushort_t)(vv.y >> 16);
      s[4] = (ushort_t)(vv.z & 0xffffu); s[5] = (ushort_t)(vv.z >> 16);
      s[6] = (ushort_t)(vv.w & 0xffffu); s[7] = (ushort_t)(vv.w >> 16);
#pragma unroll
      for (int c = 0; c < 8; ++c) vsT[c8 + c][rr] = s[c];
    }
    const int kb = TT - 1 + j0 - i0 - 31;  // kidx = kb + t, t = 31 + jj - ii
#pragma unroll
    for (int p = 0; p < 2; ++p) {  // stage r band (64 rows)
      int e = tid + 256 * p;
      int rr = e >> 3, c8 = (e & 7) * 8;
      int kidx = kb + rr;
      uint4 v = (kidx < TT) ? *(const uint4*)&r[(size_t)kidx * DM + h * DH + c8]
                            : zero4;
      *(uint4*)&rband[rr][c8] = v;
    }
    __syncthreads();

    {  // ---- phase B: AC + BDfull MFMAs, results to LDS ----
      const int acit = wv >> 1, acjt = wv & 1;
      f32x4 ac = (f32x4)(0.f);
#pragma unroll
      for (int k2 = 0; k2 < 64; k2 += 32) {
        bf16x8 a = *(const bf16x8*)&qw[acit * 16 + lm][k2 + quad * 8];
        bf16x8 b = *(const bf16x8*)&ks_[acjt * 16 + lm][k2 + quad * 8];
        ac = __builtin_amdgcn_mfma_f32_16x16x32_bf16(a, b, ac, 0, 0, 0);
      }
#pragma unroll
      for (int t = 0; t < 4; ++t)
        st[acit * 16 + quad * 4 + t][acjt * 16 + lm] = ac[t];

      const int brt = wv >> 1, bc0 = wv & 1, bc1 = (wv & 1) + 2;
      f32x4 bd0 = (f32x4)(0.f), bd1 = (f32x4)(0.f);
#pragma unroll
      for (int k2 = 0; k2 < 64; k2 += 32) {
        bf16x8 a = *(const bf16x8*)&qr[brt * 16 + lm][k2 + quad * 8];
        bf16x8 b0 = *(const bf16x8*)&rband[bc0 * 16 + lm][k2 + quad * 8];
        bf16x8 b1 = *(const bf16x8*)&rband[bc1 * 16 + lm][k2 + quad * 8];
        bd0 = __builtin_amdgcn_mfma_f32_16x16x32_bf16(a, b0, bd0, 0, 0, 0);
        bd1 = __builtin_amdgcn_mfma_f32_16x16x32_bf16(a, b1, bd1, 0, 0, 0);
      }
#pragma unroll
      for (int t = 0; t < 4; ++t) {
        bdf[brt * 16 + quad * 4 + t][bc0 * 16 + lm] = bd0[t];
        bdf[brt * 16 + quad * 4 + t][bc1 * 16 + lm] = bd1[t];
      }
    }
    __syncthreads();

    {  // ---- phase C: score assembly + online softmax (vector) ----
      const int ii = tid >> 3, g = tid & 7, jjb = g * 4;
      const int i = i0 + ii;
      float sreg[4];
#pragma unroll
      for (int u = 0; u < 4; ++u) {
        int j = j0 + jjb + u;
        float acv = st[ii][jjb + u];
        float s;
        if (j <= i) {
          s = (acv + bdf[ii][jjb + u - ii + 31]) * ATT_SCALE;
        } else {
          bool inmem = (i < NMTOK && j < NMTOK) ||
                       (i >= TT - NMTOK && j >= TT - NMTOK);
          if (!inmem) s = -1e30f;
          else if (j == i + 1) s = acv * ATT_SCALE;  // rel_shift zero-pad entry
          else {
            float b2 = 0.f;
            const int rrow = j - i - 2;
            for (int d = 0; d < 64; ++d)
              b2 += bfbits2f(((unsigned int)(ushort_t)qr[ii + 1][d]) << 16) *
                    rm[rrow][d];
            s = (acv + b2) * ATT_SCALE;
          }
        }
        sreg[u] = s;
      }
      float tmax = fmaxf(fmaxf(sreg[0], sreg[1]), fmaxf(sreg[2], sreg[3]));
#pragma unroll
      for (int off = 1; off < 8; off <<= 1) tmax = fmaxf(tmax, __shfl_xor(tmax, off));
      const float mold = m_s[ii];
      const float mnew = fmaxf(mold, tmax);
      const float alpha = expf(mold - mnew);
      float p[4], psum = 0.f;
#pragma unroll
      for (int u = 0; u < 4; ++u) { p[u] = expf(sreg[u] - mnew); psum += p[u]; }
#pragma unroll
      for (int off = 1; off < 8; off <<= 1) psum += __shfl_xor(psum, off);
      uint2 pk;
      pk.x = pack2(f2bf(p[0]), f2bf(p[1]));
      pk.y = pack2(f2bf(p[2]), f2bf(p[3]));
      *(uint2*)&pb[ii][jjb] = pk;
      if (g == 0) {
        m_s[ii] = mnew;
        l_s[ii] = l_s[ii] * alpha + psum;
        alpha_s[ii] = alpha;
      }
    }
    __syncthreads();

    {  // ---- phase D: O^T = O^T*alpha + V^T P^T ----
      const int dt = wv;
      float a0 = alpha_s[lm], a1 = alpha_s[16 + lm];
      bf16x8 av = *(const bf16x8*)&vsT[dt * 16 + lm][quad * 8];
      bf16x8 p0 = *(const bf16x8*)&pb[lm][quad * 8];
      bf16x8 p1 = *(const bf16x8*)&pb[16 + lm][quad * 8];
#pragma unroll
      for (int t = 0; t < 4; ++t) { oA[t] *= a0; oB[t] *= a1; }
      oA = __builtin_amdgcn_mfma_f32_16x16x32_bf16(av, p0, oA, 0, 0, 0);
      oB = __builtin_amdgcn_mfma_f32_16x16x32_bf16(av, p1, oB, 0, 0, 0);
    }
  }

  {  // final: scale by 1/l and store O (lane holds i=col, d=row block)
    const int dt = wv;
    float l0 = 1.f / l_s[lm], l1 = 1.f / l_s[16 + lm];
    ushort_t o0[4], o1[4];
#pragma unroll
    for (int t = 0; t < 4; ++t) {
      o0[t] = f2bf(oA[t] * l0);
      o1[t] = f2bf(oB[t] * l1);
    }
    size_t b0 = (size_t)(i0 + lm) * DM + h * DH + dt * 16 + quad * 4;
    size_t b1 = (size_t)(i0 + 16 + lm) * DM + h * DH + dt * 16 + quad * 4;
    *(uint2*)&attn[b0] = *(uint2*)o0;
    *(uint2*)&attn[b1] = *(uint2*)o1;
  }
}

// ---------------- w = LayerNorm(w + delta) * g + b; writes fp32 + bf16 ----
__global__ __launch_bounds__(256) void k_addln(float* __restrict__ w,
                                               ushort_t* __restrict__ wb,
                                               const float* __restrict__ delta,
                                               const float* __restrict__ gamma,
                                               const float* __restrict__ beta) {
  const int row = blockIdx.x;
  const int tid = threadIdx.x;
  __shared__ float red[4], red2[4];
  size_t base = (size_t)row * DM;
  float x0 = w[base + tid] + delta[base + tid];
  float x1 = w[base + tid + 256] + delta[base + tid + 256];
  float s = x0 + x1;
#pragma unroll
  for (int off = 1; off < 64; off <<= 1) s += __shfl_xor(s, off);
  if ((tid & 63) == 0) red[tid >> 6] = s;
  __syncthreads();
  float mu = (red[0] + red[1] + red[2] + red[3]) * (1.f / 512.f);
  float d0 = x0 - mu, d1 = x1 - mu;
  float v = d0 * d0 + d1 * d1;
#pragma unroll
  for (int off = 1; off < 64; off <<= 1) v += __shfl_xor(v, off);
  if ((tid & 63) == 0) red2[tid >> 6] = v;
  __syncthreads();
  float var = (red2[0] + red2[1] + red2[2] + red2[3]) * (1.f / 512.f);
  float rstd = rsqrtf(var + 1e-5f);
  float o0 = d0 * rstd * gamma[tid] + beta[tid];
  float o1 = d1 * rstd * gamma[tid + 256] + beta[tid + 256];
  w[base + tid] = o0;
  w[base + tid + 256] = o1;
  wb[base + tid] = f2bf(o0);
  wb[base + tid + 256] = f2bf(o1);
}

__global__ __launch_bounds__(256) void k_copy(const float* __restrict__ src,
                                              float* __restrict__ dst) {
  int idx = blockIdx.x * 256 + threadIdx.x;
  if (idx < TT * DM) dst[idx] = src[idx];
}

extern "C" void kernel_launch(void* const* d_in, const int* in_sizes, int n_in,
                              void* d_out, int out_size, void* d_ws, size_t ws_size,
                              hipStream_t stream) {
  const float* we   = (const float*)d_in[0];
  const float* mem  = (const float*)d_in[1];
  const float* Wqkv = (const float*)d_in[2];
  const float* Wr   = (const float*)d_in[3];
  const float* Wo   = (const float*)d_in[4];
  const float* ln1s = (const float*)d_in[5];
  const float* ln1b = (const float*)d_in[6];
  const float* W1   = (const float*)d_in[7];
  const float* b1   = (const float*)d_in[8];
  const float* W2   = (const float*)d_in[9];
  const float* b2   = (const float*)d_in[10];
  const float* ln2s = (const float*)d_in[11];
  const float* ln2b = (const float*)d_in[12];
  const float* rwb  = (const float*)d_in[13];
  const float* rrb  = (const float*)d_in[14];

  // ---- workspace layout (~25.5 MB) ----
  float* w     = (float*)d_ws;                        // TT*DM fp32
  float* proj  = w + (size_t)TT * DM;                 // TT*DM fp32 (ff2 overlays)
  ushort_t* wb    = (ushort_t*)(proj + (size_t)TT * DM);  // TT*DM bf16
  ushort_t* posb  = wb + (size_t)TT * DM;             // TT*DM bf16
  ushort_t* attnb = posb + (size_t)TT * DM;           // TT*DM bf16
  ushort_t* qkvb  = attnb + (size_t)TT * DM;          // TT*1536 bf16
  ushort_t* rbg   = qkvb + (size_t)TT * QKV_N;        // TT*DM bf16
  ushort_t* Wt    = rbg + (size_t)TT * DM;            // transposed weight (<=2048*512)
  ushort_t* ff1b  = qkvb;                             // TT*DI bf16 overlay
  float* ff2   = proj;

  k_build<<<(TT * DM + 255) / 256, 256, 0, stream>>>(we, mem, w, wb, posb);

  dim3 gQKV(QKV_N / 64, 33), gDMg(DM / 64, 33), gDIg(DI / 64, 33);
  dim3 gA(65, NH);
  dim3 tQKV(QKV_N / 32, DM / 32), tDM(DM / 32, DM / 32);
  dim3 tW1(DI / 32, DM / 32), tW2(DM / 32, DI / 32);

  for (int l = 0; l < NLAYER; ++l) {
    k_transpose<<<tQKV, 256, 0, stream>>>(Wqkv + (size_t)l * DM * QKV_N, Wt, DM, QKV_N);
    k_gemm_mfma<<<gQKV, 256, 0, stream>>>(wb, Wt, nullptr, nullptr, qkvb,
                                          TT, QKV_N, DM, 4);
    k_transpose<<<tDM, 256, 0, stream>>>(Wr + (size_t)l * DM * DM, Wt, DM, DM);
    k_gemm_mfma<<<gDMg, 256, 0, stream>>>(posb, Wt, nullptr, nullptr, rbg,
                                          TT, DM, DM, 4);
    k_attn<<<gA, 256, 0, stream>>>(qkvb, rbg, rwb, rrb, attnb);
    k_transpose<<<tDM, 256, 0, stream>>>(Wo + (size_t)l * DM * DM, Wt, DM, DM);
    k_gemm_mfma<<<gDMg, 256, 0, stream>>>(attnb, Wt, nullptr, proj, nullptr,
                                          TT, DM, DM, 0);
    k_addln<<<TT, 256, 0, stream>>>(w, wb, proj, ln1s + (size_t)l * DM, ln1b + (size_t)l * DM);
    k_transpose<<<tW1, 256, 0, stream>>>(W1 + (size_t)l * DM * DI, Wt, DM, DI);
    k_gemm_mfma<<<gDIg, 256, 0, stream>>>(wb, Wt, b1 + (size_t)l * DI, nullptr, ff1b,
                                          TT, DI, DM, 1 | 2 | 4);
    k_transpose<<<tW2, 256, 0, stream>>>(W2 + (size_t)l * DI * DM, Wt, DI, DM);
    k_gemm_mfma<<<gDMg, 256, 0, stream>>>(ff1b, Wt, b2 + (size_t)l * DM, ff2, nullptr,
                                          TT, DM, DI, 1);
    k_addln<<<TT, 256, 0, stream>>>(w, wb, ff2, ln2s + (size_t)l * DM, ln2b + (size_t)l * DM);
  }
  k_copy<<<(TT * DM + 255) / 256, 256, 0, stream>>>(w, (float*)d_out);
}

// Round 4
// 1201.715 us; speedup vs baseline: 3.9979x; 1.0173x over previous
//
#include <hip/hip_runtime.h>
#include <hip/hip_bf16.h>
#include <math.h>

#define TT 2080
#define DM 512
#define DI 2048
#define NH 8
#define DH 64
#define NMTOK 16
#define NLAYER 4
#define QKV_N 1536
#define ATT_SCALE 0.125f

typedef short bf16x8 __attribute__((ext_vector_type(8)));
typedef float f32x4 __attribute__((ext_vector_type(4)));
typedef unsigned short ushort_t;

__device__ __forceinline__ ushort_t f2bf(float f) {
  __hip_bfloat16 h = __float2bfloat16(f);
  return *reinterpret_cast<ushort_t*>(&h);
}
__device__ __forceinline__ float bfbits2f(unsigned int hi_bits) {
  return __uint_as_float(hi_bits);
}
__device__ __forceinline__ void unpack8(uint4 v, float* f) {
  f[0] = bfbits2f(v.x << 16); f[1] = bfbits2f(v.x & 0xffff0000u);
  f[2] = bfbits2f(v.y << 16); f[3] = bfbits2f(v.y & 0xffff0000u);
  f[4] = bfbits2f(v.z << 16); f[5] = bfbits2f(v.z & 0xffff0000u);
  f[6] = bfbits2f(v.w << 16); f[7] = bfbits2f(v.w & 0xffff0000u);
}
__device__ __forceinline__ unsigned int pack2(ushort_t lo, ushort_t hi) {
  return (unsigned int)lo | ((unsigned int)hi << 16);
}

// ---------------- build w (fp32+bf16) and pos_emb (bf16) ------------------
__global__ __launch_bounds__(256) void k_build(const float* __restrict__ we,
                                               const float* __restrict__ mem,
                                               float* __restrict__ w,
                                               ushort_t* __restrict__ wb,
                                               ushort_t* __restrict__ posb) {
  int idx = blockIdx.x * 256 + threadIdx.x;
  if (idx >= TT * DM) return;
  int t = idx >> 9, d = idx & 511;
  float v;
  if (t < NMTOK) v = mem[t * DM + d];
  else if (t < NMTOK + 2048) v = we[(t - NMTOK) * DM + d];
  else v = mem[(t - (NMTOK + 2048)) * DM + d];
  w[idx] = v;
  wb[idx] = f2bf(v);
  float p = (float)(TT - 1 - t);
  int i2 = d & 255;
  float freq = 1.0f / powf(10000.f, ((float)(2 * i2)) / 512.f);
  float ang = p * freq;
  posb[idx] = f2bf((d < 256) ? sinf(ang) : cosf(ang));
}

// ---- batched transpose+cast of all 5 weight mats of one layer ------------
// dst layout (shorts): QKVT@0, WRT@786432, WOT@1048576, W1T@1310720, W2T@2359296
__global__ __launch_bounds__(256) void k_transpose_all(
    const float* __restrict__ Wqkv, const float* __restrict__ Wr,
    const float* __restrict__ Wo, const float* __restrict__ W1,
    const float* __restrict__ W2, ushort_t* __restrict__ dstAll, int l) {
  __shared__ float t[32][33];
  const int tid = threadIdx.x;
  int idx = blockIdx.x;
  const float* src;
  ushort_t* dst;
  int K, N, local;
  if (idx < 768)       { src = Wqkv + (size_t)l * 512 * 1536; dst = dstAll;          K = 512;  N = 1536; local = idx; }
  else if (idx < 1024) { src = Wr   + (size_t)l * 512 * 512;  dst = dstAll + 786432; K = 512;  N = 512;  local = idx - 768; }
  else if (idx < 1280) { src = Wo   + (size_t)l * 512 * 512;  dst = dstAll + 1048576; K = 512; N = 512;  local = idx - 1024; }
  else if (idx < 2304) { src = W1   + (size_t)l * 512 * 2048; dst = dstAll + 1310720; K = 512; N = 2048; local = idx - 1280; }
  else                 { src = W2   + (size_t)l * 2048 * 512; dst = dstAll + 2359296; K = 2048; N = 512; local = idx - 2304; }
  const int ntiles = N / 32;
  const int n0 = (local % ntiles) * 32, k0 = (local / ntiles) * 32;
#pragma unroll
  for (int p = 0; p < 4; ++p) {
    int row = (tid >> 5) + 8 * p, col = tid & 31;
    t[row][col] = src[(size_t)(k0 + row) * N + n0 + col];
  }
  __syncthreads();
#pragma unroll
  for (int p = 0; p < 4; ++p) {
    int n = (tid >> 5) + 8 * p, k = tid & 31;
    dst[(size_t)(n0 + n) * K + k0 + k] = f2bf(t[k][n]);
  }
}

// ---------------- bf16 MFMA GEMM 64x64 tile: C = A @ Bt^T ------------------
// flags: 1=+bias, 2=relu, 4=bf16 output (else fp32)
__global__ __launch_bounds__(256) void k_gemm_mfma(const ushort_t* __restrict__ A,
                                                   const ushort_t* __restrict__ Bt,
                                                   const float* __restrict__ bias,
                                                   float* __restrict__ C,
                                                   ushort_t* __restrict__ Cb,
                                                   int M, int N, int K, int flags) {
  __shared__ short As[64][72];
  __shared__ short Bs[64][72];
  const int tid = threadIdx.x;
  const int m0 = blockIdx.y * 64, n0 = blockIdx.x * 64;
  const int lane = tid & 63, wv = tid >> 6;
  const int wm = (wv >> 1) * 32, wn = (wv & 1) * 32;
  const int lm = lane & 15, quad = lane >> 4;

  f32x4 acc[2][2];
#pragma unroll
  for (int a = 0; a < 2; ++a)
#pragma unroll
    for (int b = 0; b < 2; ++b) acc[a][b] = (f32x4)(0.f);

  const uint4 zero4 = make_uint4(0, 0, 0, 0);
  for (int k0 = 0; k0 < K; k0 += 64) {
    __syncthreads();
#pragma unroll
    for (int p = 0; p < 2; ++p) {
      int e = tid + 256 * p;
      int row = e >> 3, c8 = (e & 7) * 8;
      uint4 av = (m0 + row < M)
                     ? *(const uint4*)&A[(size_t)(m0 + row) * K + k0 + c8]
                     : zero4;
      *(uint4*)&As[row][c8] = av;
      uint4 bv = *(const uint4*)&Bt[(size_t)(n0 + row) * K + k0 + c8];
      *(uint4*)&Bs[row][c8] = bv;
    }
    __syncthreads();
#pragma unroll
    for (int kk = 0; kk < 64; kk += 32) {
      bf16x8 a0 = *(const bf16x8*)&As[wm + lm][kk + quad * 8];
      bf16x8 a1 = *(const bf16x8*)&As[wm + 16 + lm][kk + quad * 8];
      bf16x8 b0 = *(const bf16x8*)&Bs[wn + lm][kk + quad * 8];
      bf16x8 b1 = *(const bf16x8*)&Bs[wn + 16 + lm][kk + quad * 8];
      acc[0][0] = __builtin_amdgcn_mfma_f32_16x16x32_bf16(a0, b0, acc[0][0], 0, 0, 0);
      acc[0][1] = __builtin_amdgcn_mfma_f32_16x16x32_bf16(a0, b1, acc[0][1], 0, 0, 0);
      acc[1][0] = __builtin_amdgcn_mfma_f32_16x16x32_bf16(a1, b0, acc[1][0], 0, 0, 0);
      acc[1][1] = __builtin_amdgcn_mfma_f32_16x16x32_bf16(a1, b1, acc[1][1], 0, 0, 0);
    }
  }
#pragma unroll
  for (int mt = 0; mt < 2; ++mt)
#pragma unroll
    for (int nt = 0; nt < 2; ++nt) {
      int col = n0 + wn + nt * 16 + lm;
      float bv = (flags & 1) ? bias[col] : 0.f;
#pragma unroll
      for (int t = 0; t < 4; ++t) {
        int row = m0 + wm + mt * 16 + quad * 4 + t;
        if (row < M) {
          float v = acc[mt][nt][t] + bv;
          if (flags & 2) v = fmaxf(v, 0.f);
          if (flags & 4) Cb[(size_t)row * N + col] = f2bf(v);
          else C[(size_t)row * N + col] = v;
        }
      }
    }
}

// ---------------- bf16 MFMA GEMM 128x128 tile (big-N GEMMs) ----------------
__global__ __launch_bounds__(256) void k_gemm_mfma_big(const ushort_t* __restrict__ A,
                                                       const ushort_t* __restrict__ Bt,
                                                       const float* __restrict__ bias,
                                                       ushort_t* __restrict__ Cb,
                                                       int M, int N, int K, int flags) {
  __shared__ short As[128][72];
  __shared__ short Bs[128][72];
  const int tid = threadIdx.x;
  const int m0 = blockIdx.y * 128, n0 = blockIdx.x * 128;
  const int lane = tid & 63, wv = tid >> 6;
  const int wm = (wv >> 1) * 64, wn = (wv & 1) * 64;
  const int lm = lane & 15, quad = lane >> 4;

  f32x4 acc[4][4];
#pragma unroll
  for (int a = 0; a < 4; ++a)
#pragma unroll
    for (int b = 0; b < 4; ++b) acc[a][b] = (f32x4)(0.f);

  const uint4 zero4 = make_uint4(0, 0, 0, 0);
  for (int k0 = 0; k0 < K; k0 += 64) {
    __syncthreads();
#pragma unroll
    for (int p = 0; p < 4; ++p) {
      int e = tid + 256 * p;
      int row = e >> 3, c8 = (e & 7) * 8;
      uint4 av = (m0 + row < M)
                     ? *(const uint4*)&A[(size_t)(m0 + row) * K + k0 + c8]
                     : zero4;
      *(uint4*)&As[row][c8] = av;
      uint4 bv = *(const uint4*)&Bt[(size_t)(n0 + row) * K + k0 + c8];
      *(uint4*)&Bs[row][c8] = bv;
    }
    __syncthreads();
#pragma unroll
    for (int kk = 0; kk < 64; kk += 32) {
      bf16x8 a[4], b[4];
#pragma unroll
      for (int t = 0; t < 4; ++t) {
        a[t] = *(const bf16x8*)&As[wm + t * 16 + lm][kk + quad * 8];
        b[t] = *(const bf16x8*)&Bs[wn + t * 16 + lm][kk + quad * 8];
      }
#pragma unroll
      for (int mt = 0; mt < 4; ++mt)
#pragma unroll
        for (int nt = 0; nt < 4; ++nt)
          acc[mt][nt] =
              __builtin_amdgcn_mfma_f32_16x16x32_bf16(a[mt], b[nt], acc[mt][nt], 0, 0, 0);
    }
  }
#pragma unroll
  for (int mt = 0; mt < 4; ++mt)
#pragma unroll
    for (int nt = 0; nt < 4; ++nt) {
      int col = n0 + wn + nt * 16 + lm;
      float bv = (flags & 1) ? bias[col] : 0.f;
#pragma unroll
      for (int t = 0; t < 4; ++t) {
        int row = m0 + wm + mt * 16 + quad * 4 + t;
        if (row < M) {
          float v = acc[mt][nt][t] + bv;
          if (flags & 2) v = fmaxf(v, 0.f);
          Cb[(size_t)row * N + col] = f2bf(v);
        }
      }
    }
}

// ---------------- MFMA flash attention with XL rel-shift -------------------
__global__ __launch_bounds__(256) void k_attn(const ushort_t* __restrict__ qkv,
                                              const ushort_t* __restrict__ r,
                                              const float* __restrict__ rwb,
                                              const float* __restrict__ rrb,
                                              ushort_t* __restrict__ attn) {
  const int h = blockIdx.y;
  const int qt = 64 - blockIdx.x;  // heavy q-tiles dispatch first
  const int i0 = qt * 32;
  const int tid = threadIdx.x;
  const int lane = tid & 63, wv = tid >> 6;
  const int lm = lane & 15, quad = lane >> 4;

  __shared__ short qw[32][72];     // (q+rwb) bf16 [i][d]
  __shared__ short qr[33][72];     // (q+rrb) bf16 [i][d]
  __shared__ short ks_[32][72];    // K tile [j][d]
  __shared__ short vsT[64][70];    // V^T [d][j], stride 70 (conflict-spread)
  __shared__ short rband[64][72];  // circular r band, slot = kidx & 63
  __shared__ short pb[32][40];     // P bf16 [i][j]
  __shared__ float rm[14][68];     // r rows 0..13 fp32 (mem-block wrap)
  __shared__ float st[32][33];     // AC fp32 [i][j]
  __shared__ float bdf[32][66];    // BDfull fp32 [i][t]
  __shared__ float m_s[32], l_s[32], alpha_s[32];

  {  // stage qw/qr with bias add
    int rr = tid >> 3, c8 = (tid & 7) * 8;
    uint4 qv = *(const uint4*)&qkv[(size_t)(i0 + rr) * QKV_N + h * DH + c8];
    float f[8]; unpack8(qv, f);
    float4 w0 = *(const float4*)&rwb[h * DH + c8];
    float4 w1 = *(const float4*)&rwb[h * DH + c8 + 4];
    float4 r0 = *(const float4*)&rrb[h * DH + c8];
    float4 r1 = *(const float4*)&rrb[h * DH + c8 + 4];
    uint4 ow, orr;
    ow.x = pack2(f2bf(f[0] + w0.x), f2bf(f[1] + w0.y));
    ow.y = pack2(f2bf(f[2] + w0.z), f2bf(f[3] + w0.w));
    ow.z = pack2(f2bf(f[4] + w1.x), f2bf(f[5] + w1.y));
    ow.w = pack2(f2bf(f[6] + w1.z), f2bf(f[7] + w1.w));
    orr.x = pack2(f2bf(f[0] + r0.x), f2bf(f[1] + r0.y));
    orr.y = pack2(f2bf(f[2] + r0.z), f2bf(f[3] + r0.w));
    orr.z = pack2(f2bf(f[4] + r1.x), f2bf(f[5] + r1.y));
    orr.w = pack2(f2bf(f[6] + r1.z), f2bf(f[7] + r1.w));
    *(uint4*)&qw[rr][c8] = ow;
    *(uint4*)&qr[rr][c8] = orr;
  }
  if (tid < 112) {  // rm staging (fp32)
    int rr = tid >> 3, c8 = (tid & 7) * 8;
    uint4 v = *(const uint4*)&r[(size_t)rr * DM + h * DH + c8];
    float f[8]; unpack8(v, f);
#pragma unroll
    for (int j = 0; j < 8; ++j) rm[rr][c8 + j] = f[j];
  }
  if (tid < 32) { m_s[tid] = -INFINITY; l_s[tid] = 0.f; }

  f32x4 oA = (f32x4)(0.f);  // O^T accum, d-tile=wv, i = i0+lm
  f32x4 oB = (f32x4)(0.f);  // i = i0+16+lm

  const uint4 zero4 = make_uint4(0, 0, 0, 0);
  for (int jt = 0; jt <= qt; ++jt) {
    const int j0 = jt * 32;
    const int kb = TT - 1 + j0 - i0 - 31;  // kidx = kb + t, t = 31 + jj - ii
    __syncthreads();  // prior iteration fully done with LDS tiles
    {  // K staging: b128 row writes
      int rr = tid >> 3, c8 = (tid & 7) * 8;
      uint4 kv = *(const uint4*)&qkv[(size_t)(j0 + rr) * QKV_N + DM + h * DH + c8];
      *(uint4*)&ks_[rr][c8] = kv;
    }
    {  // V^T staging: pair-packed dword writes (conflict-free spread)
      int rr = tid >> 4;      // j-pair index 0..15
      int c4 = tid & 15;      // d-chunk of 4
      const ushort_t* v0p = &qkv[(size_t)(j0 + 2 * rr) * QKV_N + 2 * DM + h * DH + c4 * 4];
      uint2 v0 = *(const uint2*)v0p;
      uint2 v1 = *(const uint2*)(v0p + QKV_N);
      ushort_t a0 = (ushort_t)(v0.x & 0xffffu), a1 = (ushort_t)(v0.x >> 16);
      ushort_t a2 = (ushort_t)(v0.y & 0xffffu), a3 = (ushort_t)(v0.y >> 16);
      ushort_t b0 = (ushort_t)(v1.x & 0xffffu), b1 = (ushort_t)(v1.x >> 16);
      ushort_t b2 = (ushort_t)(v1.y & 0xffffu), b3 = (ushort_t)(v1.y >> 16);
      *(unsigned int*)&vsT[c4 * 4 + 0][2 * rr] = pack2(a0, b0);
      *(unsigned int*)&vsT[c4 * 4 + 1][2 * rr] = pack2(a1, b1);
      *(unsigned int*)&vsT[c4 * 4 + 2][2 * rr] = pack2(a2, b2);
      *(unsigned int*)&vsT[c4 * 4 + 3][2 * rr] = pack2(a3, b3);
    }
    if (jt == 0) {  // full 64-row band staging
#pragma unroll
      for (int p = 0; p < 2; ++p) {
        int e = tid + 256 * p;
        int t = e >> 3, c8 = (e & 7) * 8;
        int kidx = kb + t;
        uint4 v = (kidx < TT) ? *(const uint4*)&r[(size_t)kidx * DM + h * DH + c8]
                              : zero4;
        *(uint4*)&rband[kidx & 63][c8] = v;
      }
    } else {  // rolling: stage 32 new rows kb+32 .. kb+63
      int t = tid >> 3, c8 = (tid & 7) * 8;
      int kidx = kb + 32 + t;
      uint4 v = (kidx < TT) ? *(const uint4*)&r[(size_t)kidx * DM + h * DH + c8]
                            : zero4;
      *(uint4*)&rband[kidx & 63][c8] = v;
    }
    __syncthreads();

    {  // ---- phase B: AC + BDfull MFMAs -> LDS ----
      const int acit = wv >> 1, acjt = wv & 1;
      f32x4 ac = (f32x4)(0.f);
#pragma unroll
      for (int k2 = 0; k2 < 64; k2 += 32) {
        bf16x8 a = *(const bf16x8*)&qw[acit * 16 + lm][k2 + quad * 8];
        bf16x8 b = *(const bf16x8*)&ks_[acjt * 16 + lm][k2 + quad * 8];
        ac = __builtin_amdgcn_mfma_f32_16x16x32_bf16(a, b, ac, 0, 0, 0);
      }
#pragma unroll
      for (int t = 0; t < 4; ++t)
        st[acit * 16 + quad * 4 + t][acjt * 16 + lm] = ac[t];

      const int brt = wv >> 1, bc0 = wv & 1, bc1 = (wv & 1) + 2;
      const int pr0 = (kb + bc0 * 16 + lm) & 63;  // physical circular rows
      const int pr1 = (kb + bc1 * 16 + lm) & 63;
      f32x4 bd0 = (f32x4)(0.f), bd1 = (f32x4)(0.f);
#pragma unroll
      for (int k2 = 0; k2 < 64; k2 += 32) {
        bf16x8 a = *(const bf16x8*)&qr[brt * 16 + lm][k2 + quad * 8];
        bf16x8 b0 = *(const bf16x8*)&rband[pr0][k2 + quad * 8];
        bf16x8 b1 = *(const bf16x8*)&rband[pr1][k2 + quad * 8];
        bd0 = __builtin_amdgcn_mfma_f32_16x16x32_bf16(a, b0, bd0, 0, 0, 0);
        bd1 = __builtin_amdgcn_mfma_f32_16x16x32_bf16(a, b1, bd1, 0, 0, 0);
      }
#pragma unroll
      for (int t = 0; t < 4; ++t) {
        bdf[brt * 16 + quad * 4 + t][bc0 * 16 + lm] = bd0[t];
        bdf[brt * 16 + quad * 4 + t][bc1 * 16 + lm] = bd1[t];
      }
    }
    __syncthreads();

    {  // ---- phase C: score assembly + online softmax ----
      const int ii = tid >> 3, g = tid & 7, jjb = g * 4;
      const int i = i0 + ii;
      float sreg[4];
#pragma unroll
      for (int u = 0; u < 4; ++u) {
        int j = j0 + jjb + u;
        float acv = st[ii][jjb + u];
        float s;
        if (j <= i) {
          s = (acv + bdf[ii][jjb + u - ii + 31]) * ATT_SCALE;
        } else {
          bool inmem = (i < NMTOK && j < NMTOK) ||
                       (i >= TT - NMTOK && j >= TT - NMTOK);
          if (!inmem) s = -1e30f;
          else if (j == i + 1) s = acv * ATT_SCALE;  // rel_shift zero-pad entry
          else {
            float b2 = 0.f;
            const int rrow = j - i - 2;
            for (int d = 0; d < 64; ++d)
              b2 += bfbits2f(((unsigned int)(ushort_t)qr[ii + 1][d]) << 16) *
                    rm[rrow][d];
            s = (acv + b2) * ATT_SCALE;
          }
        }
        sreg[u] = s;
      }
      float tmax = fmaxf(fmaxf(sreg[0], sreg[1]), fmaxf(sreg[2], sreg[3]));
#pragma unroll
      for (int off = 1; off < 8; off <<= 1) tmax = fmaxf(tmax, __shfl_xor(tmax, off));
      const float mold = m_s[ii];
      const float mnew = fmaxf(mold, tmax);
      const float alpha = expf(mold - mnew);
      float p[4], psum = 0.f;
#pragma unroll
      for (int u = 0; u < 4; ++u) { p[u] = expf(sreg[u] - mnew); psum += p[u]; }
#pragma unroll
      for (int off = 1; off < 8; off <<= 1) psum += __shfl_xor(psum, off);
      uint2 pk;
      pk.x = pack2(f2bf(p[0]), f2bf(p[1]));
      pk.y = pack2(f2bf(p[2]), f2bf(p[3]));
      *(uint2*)&pb[ii][jjb] = pk;
      if (g == 0) {
        m_s[ii] = mnew;
        l_s[ii] = l_s[ii] * alpha + psum;
        alpha_s[ii] = alpha;
      }
    }
    __syncthreads();

    {  // ---- phase D: O^T = O^T*alpha + V^T P^T ----
      float a0 = alpha_s[lm], a1 = alpha_s[16 + lm];
      union { bf16x8 v; unsigned int u[4]; } av;
      const unsigned int* vp = (const unsigned int*)&vsT[wv * 16 + lm][quad * 8];
      av.u[0] = vp[0]; av.u[1] = vp[1]; av.u[2] = vp[2]; av.u[3] = vp[3];
      bf16x8 p0 = *(const bf16x8*)&pb[lm][quad * 8];
      bf16x8 p1 = *(const bf16x8*)&pb[16 + lm][quad * 8];
#pragma unroll
      for (int t = 0; t < 4; ++t) { oA[t] *= a0; oB[t] *= a1; }
      oA = __builtin_amdgcn_mfma_f32_16x16x32_bf16(av.v, p0, oA, 0, 0, 0);
      oB = __builtin_amdgcn_mfma_f32_16x16x32_bf16(av.v, p1, oB, 0, 0, 0);
    }
  }

  {  // final: scale by 1/l and store O (lane = i-col, quad*4 = d rows)
    float l0 = 1.f / l_s[lm], l1 = 1.f / l_s[16 + lm];
    ushort_t o0[4], o1[4];
#pragma unroll
    for (int t = 0; t < 4; ++t) {
      o0[t] = f2bf(oA[t] * l0);
      o1[t] = f2bf(oB[t] * l1);
    }
    size_t b0 = (size_t)(i0 + lm) * DM + h * DH + wv * 16 + quad * 4;
    size_t b1 = (size_t)(i0 + 16 + lm) * DM + h * DH + wv * 16 + quad * 4;
    *(uint2*)&attn[b0] = *(uint2*)o0;
    *(uint2*)&attn[b1] = *(uint2*)o1;
  }
}

// ---------------- w = LayerNorm(w + delta) * g + b; writes fp32 + bf16 ----
__global__ __launch_bounds__(256) void k_addln(float* __restrict__ w,
                                               ushort_t* __restrict__ wb,
                                               const float* __restrict__ delta,
                                               const float* __restrict__ gamma,
                                               const float* __restrict__ beta) {
  const int row = blockIdx.x;
  const int tid = threadIdx.x;
  __shared__ float red[4], red2[4];
  size_t base = (size_t)row * DM;
  float x0 = w[base + tid] + delta[base + tid];
  float x1 = w[base + tid + 256] + delta[base + tid + 256];
  float s = x0 + x1;
#pragma unroll
  for (int off = 1; off < 64; off <<= 1) s += __shfl_xor(s, off);
  if ((tid & 63) == 0) red[tid >> 6] = s;
  __syncthreads();
  float mu = (red[0] + red[1] + red[2] + red[3]) * (1.f / 512.f);
  float d0 = x0 - mu, d1 = x1 - mu;
  float v = d0 * d0 + d1 * d1;
#pragma unroll
  for (int off = 1; off < 64; off <<= 1) v += __shfl_xor(v, off);
  if ((tid & 63) == 0) red2[tid >> 6] = v;
  __syncthreads();
  float var = (red2[0] + red2[1] + red2[2] + red2[3]) * (1.f / 512.f);
  float rstd = rsqrtf(var + 1e-5f);
  float o0 = d0 * rstd * gamma[tid] + beta[tid];
  float o1 = d1 * rstd * gamma[tid + 256] + beta[tid + 256];
  w[base + tid] = o0;
  w[base + tid + 256] = o1;
  wb[base + tid] = f2bf(o0);
  wb[base + tid + 256] = f2bf(o1);
}

__global__ __launch_bounds__(256) void k_copy(const float* __restrict__ src,
                                              float* __restrict__ dst) {
  int idx = blockIdx.x * 256 + threadIdx.x;
  if (idx < TT * DM) dst[idx] = src[idx];
}

extern "C" void kernel_launch(void* const* d_in, const int* in_sizes, int n_in,
                              void* d_out, int out_size, void* d_ws, size_t ws_size,
                              hipStream_t stream) {
  const float* we   = (const float*)d_in[0];
  const float* mem  = (const float*)d_in[1];
  const float* Wqkv = (const float*)d_in[2];
  const float* Wr   = (const float*)d_in[3];
  const float* Wo   = (const float*)d_in[4];
  const float* ln1s = (const float*)d_in[5];
  const float* ln1b = (const float*)d_in[6];
  const float* W1   = (const float*)d_in[7];
  const float* b1   = (const float*)d_in[8];
  const float* W2   = (const float*)d_in[9];
  const float* b2   = (const float*)d_in[10];
  const float* ln2s = (const float*)d_in[11];
  const float* ln2b = (const float*)d_in[12];
  const float* rwb  = (const float*)d_in[13];
  const float* rrb  = (const float*)d_in[14];

  // ---- workspace layout (~30 MB) ----
  float* w     = (float*)d_ws;                        // TT*DM fp32
  float* proj  = w + (size_t)TT * DM;                 // TT*DM fp32 (ff2 overlays)
  ushort_t* wb    = (ushort_t*)(proj + (size_t)TT * DM);  // TT*DM bf16
  ushort_t* posb  = wb + (size_t)TT * DM;             // TT*DM bf16
  ushort_t* attnb = posb + (size_t)TT * DM;           // TT*DM bf16
  ushort_t* qkvb  = attnb + (size_t)TT * DM;          // TT*1536 bf16
  ushort_t* rbg   = qkvb + (size_t)TT * QKV_N;        // TT*DM bf16
  ushort_t* WtAll = rbg + (size_t)TT * DM;            // 3407872 shorts: layer's 5 mats
  ushort_t* ff1b  = qkvb;                             // TT*DI bf16 overlay
  float* ff2   = proj;
  const size_t OFF_QKVT = 0, OFF_WRT = 786432, OFF_WOT = 1048576,
               OFF_W1T = 1310720, OFF_W2T = 2359296;

  k_build<<<(TT * DM + 255) / 256, 256, 0, stream>>>(we, mem, w, wb, posb);

  dim3 gQKV(QKV_N / 128, 17), gW1(DI / 128, 17), gDMg(DM / 64, 33);
  dim3 gA(65, NH);

  for (int l = 0; l < NLAYER; ++l) {
    k_transpose_all<<<3328, 256, 0, stream>>>(Wqkv, Wr, Wo, W1, W2, WtAll, l);
    k_gemm_mfma_big<<<gQKV, 256, 0, stream>>>(wb, WtAll + OFF_QKVT, nullptr, qkvb,
                                              TT, QKV_N, DM, 4);
    k_gemm_mfma<<<gDMg, 256, 0, stream>>>(posb, WtAll + OFF_WRT, nullptr, nullptr, rbg,
                                          TT, DM, DM, 4);
    k_attn<<<gA, 256, 0, stream>>>(qkvb, rbg, rwb, rrb, attnb);
    k_gemm_mfma<<<gDMg, 256, 0, stream>>>(attnb, WtAll + OFF_WOT, nullptr, proj, nullptr,
                                          TT, DM, DM, 0);
    k_addln<<<TT, 256, 0, stream>>>(w, wb, proj, ln1s + (size_t)l * DM, ln1b + (size_t)l * DM);
    k_gemm_mfma_big<<<gW1, 256, 0, stream>>>(wb, WtAll + OFF_W1T, b1 + (size_t)l * DI, ff1b,
                                             TT, DI, DM, 1 | 2 | 4);
    k_gemm_mfma<<<gDMg, 256, 0, stream>>>(ff1b, WtAll + OFF_W2T, b2 + (size_t)l * DM, ff2, nullptr,
                                          TT, DM, DI, 1);
    k_addln<<<TT, 256, 0, stream>>>(w, wb, ff2, ln2s + (size_t)l * DM, ln2b + (size_t)l * DM);
  }
  k_copy<<<(TT * DM + 255) / 256, 256, 0, stream>>>(w, (float*)d_out);
}

// Round 5
// 1026.864 us; speedup vs baseline: 4.6787x; 1.1703x over previous
//
#include <hip/hip_runtime.h>
#include <hip/hip_bf16.h>
#include <math.h>

#define TT 2080
#define DM 512
#define DI 2048
#define NH 8
#define DH 64
#define NMTOK 16
#define NLAYER 4
#define QKV_N 1536
#define ATT_SCALE 0.125f

typedef short bf16x8 __attribute__((ext_vector_type(8)));
typedef float f32x4 __attribute__((ext_vector_type(4)));
typedef unsigned short ushort_t;

__device__ __forceinline__ ushort_t f2bf(float f) {
  __hip_bfloat16 h = __float2bfloat16(f);
  return *reinterpret_cast<ushort_t*>(&h);
}
__device__ __forceinline__ float bfbits2f(unsigned int hi_bits) {
  return __uint_as_float(hi_bits);
}
__device__ __forceinline__ void unpack8(uint4 v, float* f) {
  f[0] = bfbits2f(v.x << 16); f[1] = bfbits2f(v.x & 0xffff0000u);
  f[2] = bfbits2f(v.y << 16); f[3] = bfbits2f(v.y & 0xffff0000u);
  f[4] = bfbits2f(v.z << 16); f[5] = bfbits2f(v.z & 0xffff0000u);
  f[6] = bfbits2f(v.w << 16); f[7] = bfbits2f(v.w & 0xffff0000u);
}
__device__ __forceinline__ unsigned int pack2(ushort_t lo, ushort_t hi) {
  return (unsigned int)lo | ((unsigned int)hi << 16);
}

// ---------------- build w (fp32+bf16) and pos_emb (bf16) ------------------
__global__ __launch_bounds__(256) void k_build(const float* __restrict__ we,
                                               const float* __restrict__ mem,
                                               float* __restrict__ w,
                                               ushort_t* __restrict__ wb,
                                               ushort_t* __restrict__ posb) {
  int idx = blockIdx.x * 256 + threadIdx.x;
  if (idx >= TT * DM) return;
  int t = idx >> 9, d = idx & 511;
  float v;
  if (t < NMTOK) v = mem[t * DM + d];
  else if (t < NMTOK + 2048) v = we[(t - NMTOK) * DM + d];
  else v = mem[(t - (NMTOK + 2048)) * DM + d];
  w[idx] = v;
  wb[idx] = f2bf(v);
  float p = (float)(TT - 1 - t);
  int i2 = d & 255;
  float freq = 1.0f / powf(10000.f, ((float)(2 * i2)) / 512.f);
  float ang = p * freq;
  posb[idx] = f2bf((d < 256) ? sinf(ang) : cosf(ang));
}

// ---- batched transpose+cast of all 5 weight mats of one layer ------------
__global__ __launch_bounds__(256) void k_transpose_all(
    const float* __restrict__ Wqkv, const float* __restrict__ Wr,
    const float* __restrict__ Wo, const float* __restrict__ W1,
    const float* __restrict__ W2, ushort_t* __restrict__ dstAll, int l) {
  __shared__ float t[32][33];
  const int tid = threadIdx.x;
  int idx = blockIdx.x;
  const float* src;
  ushort_t* dst;
  int K, N, local;
  if (idx < 768)       { src = Wqkv + (size_t)l * 512 * 1536; dst = dstAll;          K = 512;  N = 1536; local = idx; }
  else if (idx < 1024) { src = Wr   + (size_t)l * 512 * 512;  dst = dstAll + 786432; K = 512;  N = 512;  local = idx - 768; }
  else if (idx < 1280) { src = Wo   + (size_t)l * 512 * 512;  dst = dstAll + 1048576; K = 512; N = 512;  local = idx - 1024; }
  else if (idx < 2304) { src = W1   + (size_t)l * 512 * 2048; dst = dstAll + 1310720; K = 512; N = 2048; local = idx - 1280; }
  else                 { src = W2   + (size_t)l * 2048 * 512; dst = dstAll + 2359296; K = 2048; N = 512; local = idx - 2304; }
  const int ntiles = N / 32;
  const int n0 = (local % ntiles) * 32, k0 = (local / ntiles) * 32;
#pragma unroll
  for (int p = 0; p < 4; ++p) {
    int row = (tid >> 5) + 8 * p, col = tid & 31;
    t[row][col] = src[(size_t)(k0 + row) * N + n0 + col];
  }
  __syncthreads();
#pragma unroll
  for (int p = 0; p < 4; ++p) {
    int n = (tid >> 5) + 8 * p, k = tid & 31;
    dst[(size_t)(n0 + n) * K + k0 + k] = f2bf(t[k][n]);
  }
}

// -------- bf16 MFMA GEMM 64x64, register-prefetch pipelined ---------------
// flags: 1=+bias, 2=relu, 4=bf16 output (else fp32)
__global__ __launch_bounds__(256) void k_gemm_mfma(const ushort_t* __restrict__ A,
                                                   const ushort_t* __restrict__ Bt,
                                                   const float* __restrict__ bias,
                                                   float* __restrict__ C,
                                                   ushort_t* __restrict__ Cb,
                                                   int M, int N, int K, int flags) {
  __shared__ short As[64][72];
  __shared__ short Bs[64][72];
  const int tid = threadIdx.x;
  const int m0 = blockIdx.y * 64, n0 = blockIdx.x * 64;
  const int lane = tid & 63, wv = tid >> 6;
  const int wm = (wv >> 1) * 32, wn = (wv & 1) * 32;
  const int lm = lane & 15, quad = lane >> 4;
  const int sr = tid >> 3, sc8 = (tid & 7) * 8;  // staging row / col chunk

  const uint4 zero4 = make_uint4(0, 0, 0, 0);
  f32x4 acc[2][2];
#pragma unroll
  for (int a = 0; a < 2; ++a)
#pragma unroll
    for (int b = 0; b < 2; ++b) acc[a][b] = (f32x4)(0.f);

  auto loadA = [&](int row, int k0) -> uint4 {
    return (m0 + row < M) ? *(const uint4*)&A[(size_t)(m0 + row) * K + k0 + sc8]
                          : zero4;
  };
  auto loadB = [&](int row, int k0) -> uint4 {
    return *(const uint4*)&Bt[(size_t)(n0 + row) * K + k0 + sc8];
  };

  uint4 a0c = loadA(sr, 0), a1c = loadA(sr + 32, 0);
  uint4 b0c = loadB(sr, 0), b1c = loadB(sr + 32, 0);

  for (int k0 = 0; k0 < K; k0 += 64) {
    const int kn = (k0 + 64 < K) ? k0 + 64 : k0;  // clamped reload on last iter
    uint4 a0n = loadA(sr, kn), a1n = loadA(sr + 32, kn);
    uint4 b0n = loadB(sr, kn), b1n = loadB(sr + 32, kn);
    __syncthreads();
    *(uint4*)&As[sr][sc8] = a0c;
    *(uint4*)&As[sr + 32][sc8] = a1c;
    *(uint4*)&Bs[sr][sc8] = b0c;
    *(uint4*)&Bs[sr + 32][sc8] = b1c;
    __syncthreads();
#pragma unroll
    for (int kk = 0; kk < 64; kk += 32) {
      bf16x8 a0 = *(const bf16x8*)&As[wm + lm][kk + quad * 8];
      bf16x8 a1 = *(const bf16x8*)&As[wm + 16 + lm][kk + quad * 8];
      bf16x8 b0 = *(const bf16x8*)&Bs[wn + lm][kk + quad * 8];
      bf16x8 b1 = *(const bf16x8*)&Bs[wn + 16 + lm][kk + quad * 8];
      acc[0][0] = __builtin_amdgcn_mfma_f32_16x16x32_bf16(a0, b0, acc[0][0], 0, 0, 0);
      acc[0][1] = __builtin_amdgcn_mfma_f32_16x16x32_bf16(a0, b1, acc[0][1], 0, 0, 0);
      acc[1][0] = __builtin_amdgcn_mfma_f32_16x16x32_bf16(a1, b0, acc[1][0], 0, 0, 0);
      acc[1][1] = __builtin_amdgcn_mfma_f32_16x16x32_bf16(a1, b1, acc[1][1], 0, 0, 0);
    }
    a0c = a0n; a1c = a1n; b0c = b0n; b1c = b1n;
  }
#pragma unroll
  for (int mt = 0; mt < 2; ++mt)
#pragma unroll
    for (int nt = 0; nt < 2; ++nt) {
      int col = n0 + wn + nt * 16 + lm;
      float bv = (flags & 1) ? bias[col] : 0.f;
#pragma unroll
      for (int t = 0; t < 4; ++t) {
        int row = m0 + wm + mt * 16 + quad * 4 + t;
        if (row < M) {
          float v = acc[mt][nt][t] + bv;
          if (flags & 2) v = fmaxf(v, 0.f);
          if (flags & 4) Cb[(size_t)row * N + col] = f2bf(v);
          else C[(size_t)row * N + col] = v;
        }
      }
    }
}

// ---------------- MFMA flash attention, register-prefetch pipelined -------
__global__ __launch_bounds__(256) void k_attn(const ushort_t* __restrict__ qkv,
                                              const ushort_t* __restrict__ r,
                                              const float* __restrict__ rwb,
                                              const float* __restrict__ rrb,
                                              ushort_t* __restrict__ attn) {
  const int h = blockIdx.y;
  const int qt = 64 - blockIdx.x;  // heavy q-tiles dispatch first
  const int i0 = qt * 32;
  const int tid = threadIdx.x;
  const int lane = tid & 63, wv = tid >> 6;
  const int lm = lane & 15, quad = lane >> 4;

  __shared__ short qw[32][72];     // (q+rwb) bf16 [i][d]
  __shared__ short qr[33][72];     // (q+rrb) bf16 [i][d]
  __shared__ short ks_[32][72];    // K tile [j][d]
  __shared__ short vsT[64][70];    // V^T [d][j]
  __shared__ short rband[64][72];  // circular r band, slot = kidx & 63
  __shared__ short pb[32][40];     // P bf16 [i][j]
  __shared__ float rm[14][68];     // r rows 0..13 fp32 (mem-block wrap)
  __shared__ float st[32][33];     // AC fp32 [i][j]
  __shared__ float bdf[32][66];    // BDfull fp32 [i][t]
  __shared__ float m_s[32], l_s[32], alpha_s[32];

  const uint4 zero4 = make_uint4(0, 0, 0, 0);
  const int krr = tid >> 3, kc8 = (tid & 7) * 8;  // K/rband staging coords
  const int vrr = tid >> 4, vc4 = tid & 15;       // V staging coords
  const int kb0 = TT - 32 - i0;

  auto loadK = [&](int j0) -> uint4 {
    return *(const uint4*)&qkv[(size_t)(j0 + krr) * QKV_N + DM + h * DH + kc8];
  };
  auto loadBand = [&](int kidx) -> uint4 {
    return (kidx < TT) ? *(const uint4*)&r[(size_t)kidx * DM + h * DH + kc8]
                       : zero4;
  };

  {  // stage qw/qr with bias add
    int rr = tid >> 3, c8 = (tid & 7) * 8;
    uint4 qv = *(const uint4*)&qkv[(size_t)(i0 + rr) * QKV_N + h * DH + c8];
    float f[8]; unpack8(qv, f);
    float4 w0 = *(const float4*)&rwb[h * DH + c8];
    float4 w1 = *(const float4*)&rwb[h * DH + c8 + 4];
    float4 r0 = *(const float4*)&rrb[h * DH + c8];
    float4 r1 = *(const float4*)&rrb[h * DH + c8 + 4];
    uint4 ow, orr;
    ow.x = pack2(f2bf(f[0] + w0.x), f2bf(f[1] + w0.y));
    ow.y = pack2(f2bf(f[2] + w0.z), f2bf(f[3] + w0.w));
    ow.z = pack2(f2bf(f[4] + w1.x), f2bf(f[5] + w1.y));
    ow.w = pack2(f2bf(f[6] + w1.z), f2bf(f[7] + w1.w));
    orr.x = pack2(f2bf(f[0] + r0.x), f2bf(f[1] + r0.y));
    orr.y = pack2(f2bf(f[2] + r0.z), f2bf(f[3] + r0.w));
    orr.z = pack2(f2bf(f[4] + r1.x), f2bf(f[5] + r1.y));
    orr.w = pack2(f2bf(f[6] + r1.z), f2bf(f[7] + r1.w));
    *(uint4*)&qw[rr][c8] = ow;
    *(uint4*)&qr[rr][c8] = orr;
  }
  if (tid < 112) {  // rm staging (fp32)
    int rr = tid >> 3, c8 = (tid & 7) * 8;
    uint4 v = *(const uint4*)&r[(size_t)rr * DM + h * DH + c8];
    float f[8]; unpack8(v, f);
#pragma unroll
    for (int j = 0; j < 8; ++j) rm[rr][c8 + j] = f[j];
  }
  if (tid < 32) { m_s[tid] = -INFINITY; l_s[tid] = 0.f; }

  f32x4 oA = (f32x4)(0.f);  // O^T accum, d-tile=wv, i = i0+lm
  f32x4 oB = (f32x4)(0.f);  // i = i0+16+lm

  // ---- pipeline prologue: tile 0 into registers ----
  uint4 kcur = loadK(0);
  const ushort_t* vp0 = &qkv[(size_t)(2 * vrr) * QKV_N + 2 * DM + h * DH + vc4 * 4];
  uint2 v0cur = *(const uint2*)vp0, v1cur = *(const uint2*)(vp0 + QKV_N);
  uint4 band0 = loadBand(kb0 + krr);
  uint4 band1 = loadBand(kb0 + 32 + krr);
  uint4 bcur = zero4;

  for (int jt = 0; jt <= qt; ++jt) {
    const int j0 = jt * 32;
    const int kb = kb0 + 32 * jt;
    // ---- issue next tile's loads (clamped reload on last iteration) ----
    const int jn = (jt < qt) ? j0 + 32 : j0;
    uint4 knext = loadK(jn);
    const ushort_t* vpn = &qkv[(size_t)(jn + 2 * vrr) * QKV_N + 2 * DM + h * DH + vc4 * 4];
    uint2 v0n = *(const uint2*)vpn, v1n = *(const uint2*)(vpn + QKV_N);
    uint4 bnext = loadBand((jt < qt) ? (kb + 64 + krr) : (kb0 + krr));

    __syncthreads();  // prior iteration fully done with LDS tiles
    // ---- write current tile (loaded last iteration) to LDS ----
    *(uint4*)&ks_[krr][kc8] = kcur;
    {
      ushort_t a0 = (ushort_t)(v0cur.x & 0xffffu), a1 = (ushort_t)(v0cur.x >> 16);
      ushort_t a2 = (ushort_t)(v0cur.y & 0xffffu), a3 = (ushort_t)(v0cur.y >> 16);
      ushort_t c0 = (ushort_t)(v1cur.x & 0xffffu), c1 = (ushort_t)(v1cur.x >> 16);
      ushort_t c2 = (ushort_t)(v1cur.y & 0xffffu), c3 = (ushort_t)(v1cur.y >> 16);
      *(unsigned int*)&vsT[vc4 * 4 + 0][2 * vrr] = pack2(a0, c0);
      *(unsigned int*)&vsT[vc4 * 4 + 1][2 * vrr] = pack2(a1, c1);
      *(unsigned int*)&vsT[vc4 * 4 + 2][2 * vrr] = pack2(a2, c2);
      *(unsigned int*)&vsT[vc4 * 4 + 3][2 * vrr] = pack2(a3, c3);
    }
    if (jt == 0) {
      *(uint4*)&rband[(kb0 + krr) & 63][kc8] = band0;
      *(uint4*)&rband[(kb0 + 32 + krr) & 63][kc8] = band1;
    } else {
      *(uint4*)&rband[(kb + 32 + krr) & 63][kc8] = bcur;
    }
    __syncthreads();

    {  // ---- phase B: AC + BDfull MFMAs -> LDS ----
      const int acit = wv >> 1, acjt = wv & 1;
      f32x4 ac = (f32x4)(0.f);
#pragma unroll
      for (int k2 = 0; k2 < 64; k2 += 32) {
        bf16x8 a = *(const bf16x8*)&qw[acit * 16 + lm][k2 + quad * 8];
        bf16x8 b = *(const bf16x8*)&ks_[acjt * 16 + lm][k2 + quad * 8];
        ac = __builtin_amdgcn_mfma_f32_16x16x32_bf16(a, b, ac, 0, 0, 0);
      }
#pragma unroll
      for (int t = 0; t < 4; ++t)
        st[acit * 16 + quad * 4 + t][acjt * 16 + lm] = ac[t];

      const int brt = wv >> 1, bc0 = wv & 1, bc1 = (wv & 1) + 2;
      const int pr0 = (kb + bc0 * 16 + lm) & 63;  // physical circular rows
      const int pr1 = (kb + bc1 * 16 + lm) & 63;
      f32x4 bd0 = (f32x4)(0.f), bd1 = (f32x4)(0.f);
#pragma unroll
      for (int k2 = 0; k2 < 64; k2 += 32) {
        bf16x8 a = *(const bf16x8*)&qr[brt * 16 + lm][k2 + quad * 8];
        bf16x8 b0 = *(const bf16x8*)&rband[pr0][k2 + quad * 8];
        bf16x8 b1 = *(const bf16x8*)&rband[pr1][k2 + quad * 8];
        bd0 = __builtin_amdgcn_mfma_f32_16x16x32_bf16(a, b0, bd0, 0, 0, 0);
        bd1 = __builtin_amdgcn_mfma_f32_16x16x32_bf16(a, b1, bd1, 0, 0, 0);
      }
#pragma unroll
      for (int t = 0; t < 4; ++t) {
        bdf[brt * 16 + quad * 4 + t][bc0 * 16 + lm] = bd0[t];
        bdf[brt * 16 + quad * 4 + t][bc1 * 16 + lm] = bd1[t];
      }
    }
    __syncthreads();

    {  // ---- phase C: score assembly + online softmax ----
      const int ii = tid >> 3, g = tid & 7, jjb = g * 4;
      const int i = i0 + ii;
      float sreg[4];
#pragma unroll
      for (int u = 0; u < 4; ++u) {
        int j = j0 + jjb + u;
        float acv = st[ii][jjb + u];
        float s;
        if (j <= i) {
          s = (acv + bdf[ii][jjb + u - ii + 31]) * ATT_SCALE;
        } else {
          bool inmem = (i < NMTOK && j < NMTOK) ||
                       (i >= TT - NMTOK && j >= TT - NMTOK);
          if (!inmem) s = -1e30f;
          else if (j == i + 1) s = acv * ATT_SCALE;  // rel_shift zero-pad entry
          else {
            float b2 = 0.f;
            const int rrow = j - i - 2;
            for (int d = 0; d < 64; ++d)
              b2 += bfbits2f(((unsigned int)(ushort_t)qr[ii + 1][d]) << 16) *
                    rm[rrow][d];
            s = (acv + b2) * ATT_SCALE;
          }
        }
        sreg[u] = s;
      }
      float tmax = fmaxf(fmaxf(sreg[0], sreg[1]), fmaxf(sreg[2], sreg[3]));
#pragma unroll
      for (int off = 1; off < 8; off <<= 1) tmax = fmaxf(tmax, __shfl_xor(tmax, off));
      const float mold = m_s[ii];
      const float mnew = fmaxf(mold, tmax);
      const float alpha = __expf(mold - mnew);
      float p[4], psum = 0.f;
#pragma unroll
      for (int u = 0; u < 4; ++u) { p[u] = __expf(sreg[u] - mnew); psum += p[u]; }
#pragma unroll
      for (int off = 1; off < 8; off <<= 1) psum += __shfl_xor(psum, off);
      uint2 pk;
      pk.x = pack2(f2bf(p[0]), f2bf(p[1]));
      pk.y = pack2(f2bf(p[2]), f2bf(p[3]));
      *(uint2*)&pb[ii][jjb] = pk;
      if (g == 0) {
        m_s[ii] = mnew;
        l_s[ii] = l_s[ii] * alpha + psum;
        alpha_s[ii] = alpha;
      }
    }
    __syncthreads();

    {  // ---- phase D: O^T = O^T*alpha + V^T P^T ----
      float a0 = alpha_s[lm], a1 = alpha_s[16 + lm];
      union { bf16x8 v; unsigned int u[4]; } av;
      const unsigned int* vp = (const unsigned int*)&vsT[wv * 16 + lm][quad * 8];
      av.u[0] = vp[0]; av.u[1] = vp[1]; av.u[2] = vp[2]; av.u[3] = vp[3];
      bf16x8 p0 = *(const bf16x8*)&pb[lm][quad * 8];
      bf16x8 p1 = *(const bf16x8*)&pb[16 + lm][quad * 8];
#pragma unroll
      for (int t = 0; t < 4; ++t) { oA[t] *= a0; oB[t] *= a1; }
      oA = __builtin_amdgcn_mfma_f32_16x16x32_bf16(av.v, p0, oA, 0, 0, 0);
      oB = __builtin_amdgcn_mfma_f32_16x16x32_bf16(av.v, p1, oB, 0, 0, 0);
    }
    kcur = knext; v0cur = v0n; v1cur = v1n; bcur = bnext;
  }

  {  // final: scale by 1/l and store O (lane = i-col, quad*4 = d rows)
    float l0 = 1.f / l_s[lm], l1 = 1.f / l_s[16 + lm];
    ushort_t o0[4], o1[4];
#pragma unroll
    for (int t = 0; t < 4; ++t) {
      o0[t] = f2bf(oA[t] * l0);
      o1[t] = f2bf(oB[t] * l1);
    }
    size_t b0 = (size_t)(i0 + lm) * DM + h * DH + wv * 16 + quad * 4;
    size_t b1 = (size_t)(i0 + 16 + lm) * DM + h * DH + wv * 16 + quad * 4;
    *(uint2*)&attn[b0] = *(uint2*)o0;
    *(uint2*)&attn[b1] = *(uint2*)o1;
  }
}

// ---------------- w = LayerNorm(w + delta) * g + b; writes fp32 + bf16 ----
__global__ __launch_bounds__(256) void k_addln(float* __restrict__ w,
                                               ushort_t* __restrict__ wb,
                                               const float* __restrict__ delta,
                                               const float* __restrict__ gamma,
                                               const float* __restrict__ beta) {
  const int row = blockIdx.x;
  const int tid = threadIdx.x;
  __shared__ float red[4], red2[4];
  size_t base = (size_t)row * DM;
  float x0 = w[base + tid] + delta[base + tid];
  float x1 = w[base + tid + 256] + delta[base + tid + 256];
  float s = x0 + x1;
#pragma unroll
  for (int off = 1; off < 64; off <<= 1) s += __shfl_xor(s, off);
  if ((tid & 63) == 0) red[tid >> 6] = s;
  __syncthreads();
  float mu = (red[0] + red[1] + red[2] + red[3]) * (1.f / 512.f);
  float d0 = x0 - mu, d1 = x1 - mu;
  float v = d0 * d0 + d1 * d1;
#pragma unroll
  for (int off = 1; off < 64; off <<= 1) v += __shfl_xor(v, off);
  if ((tid & 63) == 0) red2[tid >> 6] = v;
  __syncthreads();
  float var = (red2[0] + red2[1] + red2[2] + red2[3]) * (1.f / 512.f);
  float rstd = rsqrtf(var + 1e-5f);
  float o0 = d0 * rstd * gamma[tid] + beta[tid];
  float o1 = d1 * rstd * gamma[tid + 256] + beta[tid + 256];
  w[base + tid] = o0;
  w[base + tid + 256] = o1;
  wb[base + tid] = f2bf(o0);
  wb[base + tid + 256] = f2bf(o1);
}

__global__ __launch_bounds__(256) void k_copy(const float* __restrict__ src,
                                              float* __restrict__ dst) {
  int idx = blockIdx.x * 256 + threadIdx.x;
  if (idx < TT * DM) dst[idx] = src[idx];
}

extern "C" void kernel_launch(void* const* d_in, const int* in_sizes, int n_in,
                              void* d_out, int out_size, void* d_ws, size_t ws_size,
                              hipStream_t stream) {
  const float* we   = (const float*)d_in[0];
  const float* mem  = (const float*)d_in[1];
  const float* Wqkv = (const float*)d_in[2];
  const float* Wr   = (const float*)d_in[3];
  const float* Wo   = (const float*)d_in[4];
  const float* ln1s = (const float*)d_in[5];
  const float* ln1b = (const float*)d_in[6];
  const float* W1   = (const float*)d_in[7];
  const float* b1   = (const float*)d_in[8];
  const float* W2   = (const float*)d_in[9];
  const float* b2   = (const float*)d_in[10];
  const float* ln2s = (const float*)d_in[11];
  const float* ln2b = (const float*)d_in[12];
  const float* rwb  = (const float*)d_in[13];
  const float* rrb  = (const float*)d_in[14];

  // ---- workspace layout (~30 MB) ----
  float* w     = (float*)d_ws;                        // TT*DM fp32
  float* proj  = w + (size_t)TT * DM;                 // TT*DM fp32 (ff2 overlays)
  ushort_t* wb    = (ushort_t*)(proj + (size_t)TT * DM);  // TT*DM bf16
  ushort_t* posb  = wb + (size_t)TT * DM;             // TT*DM bf16
  ushort_t* attnb = posb + (size_t)TT * DM;           // TT*DM bf16
  ushort_t* qkvb  = attnb + (size_t)TT * DM;          // TT*1536 bf16
  ushort_t* rbg   = qkvb + (size_t)TT * QKV_N;        // TT*DM bf16
  ushort_t* WtAll = rbg + (size_t)TT * DM;            // 3407872 shorts: layer's 5 mats
  ushort_t* ff1b  = qkvb;                             // TT*DI bf16 overlay
  float* ff2   = proj;
  const size_t OFF_QKVT = 0, OFF_WRT = 786432, OFF_WOT = 1048576,
               OFF_W1T = 1310720, OFF_W2T = 2359296;

  k_build<<<(TT * DM + 255) / 256, 256, 0, stream>>>(we, mem, w, wb, posb);

  dim3 gQKV(QKV_N / 64, 33), gDMg(DM / 64, 33), gDIg(DI / 64, 33);
  dim3 gA(65, NH);

  for (int l = 0; l < NLAYER; ++l) {
    k_transpose_all<<<3328, 256, 0, stream>>>(Wqkv, Wr, Wo, W1, W2, WtAll, l);
    k_gemm_mfma<<<gQKV, 256, 0, stream>>>(wb, WtAll + OFF_QKVT, nullptr, nullptr, qkvb,
                                          TT, QKV_N, DM, 4);
    k_gemm_mfma<<<gDMg, 256, 0, stream>>>(posb, WtAll + OFF_WRT, nullptr, nullptr, rbg,
                                          TT, DM, DM, 4);
    k_attn<<<gA, 256, 0, stream>>>(qkvb, rbg, rwb, rrb, attnb);
    k_gemm_mfma<<<gDMg, 256, 0, stream>>>(attnb, WtAll + OFF_WOT, nullptr, proj, nullptr,
                                          TT, DM, DM, 0);
    k_addln<<<TT, 256, 0, stream>>>(w, wb, proj, ln1s + (size_t)l * DM, ln1b + (size_t)l * DM);
    k_gemm_mfma<<<gDIg, 256, 0, stream>>>(wb, WtAll + OFF_W1T, b1 + (size_t)l * DI, nullptr, ff1b,
                                          TT, DI, DM, 1 | 2 | 4);
    k_gemm_mfma<<<gDMg, 256, 0, stream>>>(ff1b, WtAll + OFF_W2T, b2 + (size_t)l * DM, ff2, nullptr,
                                          TT, DM, DI, 1);
    k_addln<<<TT, 256, 0, stream>>>(w, wb, ff2, ln2s + (size_t)l * DM, ln2b + (size_t)l * DM);
  }
  k_copy<<<(TT * DM + 255) / 256, 256, 0, stream>>>(w, (float*)d_out);
}